// Round 2
// baseline (1156.094 us; speedup 1.0000x reference)
//
#include <hip/hip_runtime.h>
#include <hip/hip_bf16.h>
#include <cstdint>

#define NB    16384
#define DIMX  2048
#define STATE 2048
#define SELH  1024

typedef unsigned short u16;
typedef short  short8_t __attribute__((ext_vector_type(8)));
typedef float  f32x4    __attribute__((ext_vector_type(4)));

__device__ __forceinline__ u16 f2bf(float f) {
  unsigned u = __builtin_bit_cast(unsigned, f);
  u += 0x7fffu + ((u >> 16) & 1u);   // RNE
  return (u16)(u >> 16);
}
__device__ __forceinline__ float bf2f(u16 h) {
  unsigned u = ((unsigned)h) << 16;
  return __builtin_bit_cast(float, u);
}
__device__ __forceinline__ float sigmoidf_(float x) { return 1.f / (1.f + __expf(-x)); }
__device__ __forceinline__ float tanhf_(float x)    { return 2.f / (1.f + __expf(-2.f * x)) - 1.f; }

__device__ __forceinline__ f32x4 mfma_bf16(short8_t a, short8_t b, f32x4 c) {
  return __builtin_amdgcn_mfma_f32_16x16x32_bf16(a, b, c, 0, 0, 0);
}

// ---- async global->LDS, 16B per lane ----
__device__ __forceinline__ void gload16(const void* g, const void* l) {
  __builtin_amdgcn_global_load_lds(
      (const __attribute__((address_space(1))) unsigned int*)(uintptr_t)g,
      (__attribute__((address_space(3))) unsigned int*)(unsigned int)(uintptr_t)l,
      16, 0, 0);
}

// ---- f32 -> bf16 convert, vectorized ----
__global__ __launch_bounds__(256) void k_f32_to_bf16(const float* __restrict__ src,
                                                     u16* __restrict__ dst, int n4) {
  int i = blockIdx.x * blockDim.x + threadIdx.x;
  int stride = gridDim.x * blockDim.x;
  for (; i < n4; i += stride) {
    float4 v = ((const float4*)src)[i];
    ushort4 o;
    o.x = f2bf(v.x); o.y = f2bf(v.y); o.z = f2bf(v.z); o.w = f2bf(v.w);
    ((ushort4*)dst)[i] = o;
  }
}

// ---- GEMM: C[M,N] = A[M,K] * B[N,K]^T  (bf16 in, f32 acc) ----
// EPI: 0 = store bf16 (u)           1 = silu -> bf16 (sel_h)
//      2 = store f32 (final out)
//      3 = dual quadrants a,b : h_t = sigmoid(a)*h_prev + tanh(b)*u  -> f32out
//      4 = dual quadrants c,d : y   = tanh(c)*h_t + d[s]*sigmoid(dd)*u -> bf16out
// dual: BN=128 tile = [64 cols of quadrant q0 | 64 cols of quadrant q0+1], state cols = blockIdx.x*64..+63
template <int EPI>
__global__ __launch_bounds__(256) void k_gemm(const u16* __restrict__ A,
                                              const u16* __restrict__ Bsrc,
                                              int K, int Ncols,
                                              float* __restrict__ f32out,
                                              u16* __restrict__ bfout,
                                              const float* __restrict__ hprev,
                                              const u16* __restrict__ ubf,
                                              const float* __restrict__ dvec) {
  extern __shared__ __align__(16) char smem[];   // [0,8192) A tile, [8192,16384) B tile
  const int tid = threadIdx.x;
  const int w = tid >> 6;      // wave 0..3
  const int l = tid & 63;      // lane
  const int i_half = w >> 1;   // row half
  const int j_mat  = w & 1;    // col half / matrix select (dual)
  const int wm = i_half * 64;
  const int wn = j_mat * 64;
  const int m0 = blockIdx.y * 128;

  // ---- staging addressing (per-thread, loop-invariant) ----
  const int r0 = w * 32 + (l >> 2);  // tile row for instr 0
  const int r1 = r0 + 16;            // tile row for instr 1
  const int c8 = (l & 3) * 8;        // k-offset (elements)
  const size_t aoff0 = ((size_t)(m0 + r0) * K + c8) * 2;
  const size_t aoff1 = ((size_t)(m0 + r1) * K + c8) * 2;
  size_t boff0, boff1;
  if constexpr (EPI <= 2) {
    const int n0 = blockIdx.x * 128;
    boff0 = ((size_t)(n0 + r0) * K + c8) * 2;
    boff1 = ((size_t)(n0 + r1) * K + c8) * 2;
  } else {
    const int n0s = blockIdx.x * 64;
    const int q0 = (EPI == 3) ? 0 : 2;
    boff0 = ((size_t)((q0 + (r0 >> 6)) * STATE + n0s + (r0 & 63)) * K + c8) * 2;
    boff1 = ((size_t)((q0 + (r1 >> 6)) * STATE + n0s + (r1 & 63)) * K + c8) * 2;
  }
  const char* gA = (const char*)A;
  const char* gB = (const char*)Bsrc;
  const unsigned la0 = (unsigned)(w * 2048 + l * 16);
  const unsigned la1 = la0 + 1024;
  const unsigned lb0 = 8192u + la0;
  const unsigned lb1 = 8192u + la1;

  f32x4 acc[4][4];
#pragma unroll
  for (int a = 0; a < 4; ++a)
#pragma unroll
    for (int b = 0; b < 4; ++b) acc[a][b] = f32x4{0.f, 0.f, 0.f, 0.f};

  const char* Apf = smem + (size_t)(wm + (l & 15)) * 64 + (l >> 4) * 16;
  const char* Bpf = smem + 8192 + (size_t)(wn + (l & 15)) * 64 + (l >> 4) * 16;

  for (int k0 = 0; k0 < K; k0 += 32) {
    const size_t kb = (size_t)k0 * 2;
    gload16(gA + aoff0 + kb, smem + la0);
    gload16(gA + aoff1 + kb, smem + la1);
    gload16(gB + boff0 + kb, smem + lb0);
    gload16(gB + boff1 + kb, smem + lb1);
    asm volatile("s_waitcnt vmcnt(0)" ::: "memory");
    __syncthreads();

    short8_t av[4], bv[4];
#pragma unroll
    for (int t = 0; t < 4; ++t) {
      av[t] = *(const short8_t*)(Apf + t * 1024);
      bv[t] = *(const short8_t*)(Bpf + t * 1024);
    }
#pragma unroll
    for (int im = 0; im < 4; ++im)
#pragma unroll
      for (int in = 0; in < 4; ++in)
        acc[im][in] = mfma_bf16(av[im], bv[in], acc[im][in]);
    __syncthreads();
  }

  const int lr0 = (l >> 4) << 2;   // C-frag row base within 16x16
  const int lc0 = l & 15;          // C-frag col

  if constexpr (EPI <= 2) {
    const int n0 = blockIdx.x * 128;
    const int row_base = blockIdx.y * 128 + wm + lr0;
    const int col_base = n0 + wn + lc0;
#pragma unroll
    for (int im = 0; im < 4; ++im)
#pragma unroll
      for (int in = 0; in < 4; ++in)
#pragma unroll
        for (int r = 0; r < 4; ++r) {
          const int row = row_base + im * 16 + r;
          const int col = col_base + in * 16;
          const size_t idx = (size_t)row * Ncols + col;
          float v = acc[im][in][r];
          if constexpr (EPI == 0) {
            bfout[idx] = f2bf(v);
          } else if constexpr (EPI == 1) {
            bfout[idx] = f2bf(v * sigmoidf_(v));
          } else {
            f32out[idx] = v;
          }
        }
  } else {
    // dual: wave j=1 ships its (b or d) accumulators through LDS to wave j=0
    float* xch = (float*)smem;     // 2 x [64][65] f32, aliases staged tiles (safe: past last barrier)
    if (j_mat == 1) {
#pragma unroll
      for (int im = 0; im < 4; ++im)
#pragma unroll
        for (int in = 0; in < 4; ++in)
#pragma unroll
          for (int r = 0; r < 4; ++r)
            xch[i_half * 4160 + (im * 16 + lr0 + r) * 65 + in * 16 + lc0] = acc[im][in][r];
    }
    __syncthreads();
    if (j_mat == 0) {
      const int n0s = blockIdx.x * 64;
#pragma unroll
      for (int im = 0; im < 4; ++im)
#pragma unroll
        for (int in = 0; in < 4; ++in)
#pragma unroll
          for (int r = 0; r < 4; ++r) {
            const int lrow = im * 16 + lr0 + r;
            const int lcol = in * 16 + lc0;
            const float own = acc[im][in][r];                       // a_raw or c_raw
            const float oth = xch[i_half * 4160 + lrow * 65 + lcol]; // b_raw or d_raw
            const int grow = blockIdx.y * 128 + i_half * 64 + lrow;
            const int s = n0s + lcol;
            const size_t idx = (size_t)grow * STATE + s;
            const float uu = bf2f(ubf[idx]);
            if constexpr (EPI == 3) {
              const float at = sigmoidf_(own);
              const float bt = tanhf_(oth);
              f32out[idx] = at * hprev[idx] + bt * uu;              // h_t
            } else {
              const float ct = tanhf_(own);
              const float dt = sigmoidf_(oth);
              bfout[idx] = f2bf(ct * hprev[idx] + dvec[s] * dt * uu); // y (hprev = h_t here)
            }
          }
    }
  }
}

extern "C" void kernel_launch(void* const* d_in, const int* in_sizes, int n_in,
                              void* d_out, int out_size, void* d_ws, size_t ws_size,
                              hipStream_t stream) {
  const float* x   = (const float*)d_in[0];
  const float* h0  = (const float*)d_in[1];
  const float* Win = (const float*)d_in[2];
  const float* Wsi = (const float*)d_in[3];
  const float* Wso = (const float*)d_in[4];
  const float* Wou = (const float*)d_in[5];
  const float* dv  = (const float*)d_in[6];
  float* out  = (float*)d_out;
  float* hout = out + (size_t)NB * DIMX;   // second output: h_t

  u16* ws = (u16*)d_ws;
  size_t o = 0;
  u16* xb   = ws + o; o += (size_t)NB * DIMX;        // x bf16
  u16* ub   = ws + o; o += (size_t)NB * STATE;       // u bf16
  u16* yb   = ws + o; o += (size_t)NB * STATE;       // y bf16
  u16* sh   = ws + o; o += (size_t)NB * SELH;        // sel_h bf16
  u16* wib  = ws + o; o += (size_t)STATE * DIMX;     // W_in bf16
  u16* wsib = ws + o; o += (size_t)SELH * DIMX;      // W_sel_in bf16
  u16* wsob = ws + o; o += (size_t)4 * STATE * SELH; // W_sel_out bf16
  u16* wob  = ws + o; o += (size_t)DIMX * STATE;     // W_out bf16

  k_f32_to_bf16<<<1024, 256, 0, stream>>>(x,   xb,   NB * DIMX / 4);
  k_f32_to_bf16<<<256,  256, 0, stream>>>(Win, wib,  STATE * DIMX / 4);
  k_f32_to_bf16<<<128,  256, 0, stream>>>(Wsi, wsib, SELH * DIMX / 4);
  k_f32_to_bf16<<<512,  256, 0, stream>>>(Wso, wsob, 4 * STATE * SELH / 4);
  k_f32_to_bf16<<<256,  256, 0, stream>>>(Wou, wob,  DIMX * STATE / 4);

  const dim3 blk(256);
  // u = x @ W_in^T
  k_gemm<0><<<dim3(STATE / 128, NB / 128), blk, 16384, stream>>>(
      xb, wib, DIMX, STATE, nullptr, ub, nullptr, nullptr, nullptr);
  // sel_h = silu(x @ W_sel_in^T)
  k_gemm<1><<<dim3(SELH / 128, NB / 128), blk, 16384, stream>>>(
      xb, wsib, DIMX, SELH, nullptr, sh, nullptr, nullptr, nullptr);
  // h_t = sigmoid(a)*h_prev + tanh(b)*u   (a,b quadrants of sel)
  k_gemm<3><<<dim3(STATE / 64, NB / 128), blk, 33280, stream>>>(
      sh, wsob, SELH, 0, hout, nullptr, h0, ub, nullptr);
  // y = tanh(c)*h_t + d*sigmoid(dd)*u     (c,d quadrants of sel)
  k_gemm<4><<<dim3(STATE / 64, NB / 128), blk, 33280, stream>>>(
      sh, wsob, SELH, 0, nullptr, yb, hout, ub, dv);
  // out = y @ W_out^T
  k_gemm<2><<<dim3(DIMX / 128, NB / 128), blk, 16384, stream>>>(
      yb, wob, STATE, DIMX, out, nullptr, nullptr, nullptr, nullptr);
}

// Round 3
// 1102.111 us; speedup vs baseline: 1.0490x; 1.0490x over previous
//
#include <hip/hip_runtime.h>
#include <hip/hip_bf16.h>
#include <cstdint>

#define NB    16384
#define DIMX  2048
#define STATE 2048
#define SELH  1024

typedef unsigned short u16;
typedef short  short8_t __attribute__((ext_vector_type(8)));
typedef float  f32x4    __attribute__((ext_vector_type(4)));

__device__ __forceinline__ u16 f2bf(float f) {
  unsigned u = __builtin_bit_cast(unsigned, f);
  u += 0x7fffu + ((u >> 16) & 1u);   // RNE
  return (u16)(u >> 16);
}
__device__ __forceinline__ float bf2f(u16 h) {
  unsigned u = ((unsigned)h) << 16;
  return __builtin_bit_cast(float, u);
}
__device__ __forceinline__ float sigmoidf_(float x) { return 1.f / (1.f + __expf(-x)); }
__device__ __forceinline__ float tanhf_(float x)    { return 2.f / (1.f + __expf(-2.f * x)) - 1.f; }

__device__ __forceinline__ f32x4 mfma_bf16(short8_t a, short8_t b, f32x4 c) {
  return __builtin_amdgcn_mfma_f32_16x16x32_bf16(a, b, c, 0, 0, 0);
}

// ---- async global->LDS, 16B per lane ----
__device__ __forceinline__ void gload16(const void* g, const void* l) {
  __builtin_amdgcn_global_load_lds(
      (const __attribute__((address_space(1))) unsigned int*)(uintptr_t)g,
      (__attribute__((address_space(3))) unsigned int*)(unsigned int)(uintptr_t)l,
      16, 0, 0);
}

// ---- f32 -> bf16 convert, vectorized ----
__global__ __launch_bounds__(256) void k_f32_to_bf16(const float* __restrict__ src,
                                                     u16* __restrict__ dst, int n4) {
  int i = blockIdx.x * blockDim.x + threadIdx.x;
  int stride = gridDim.x * blockDim.x;
  for (; i < n4; i += stride) {
    float4 v = ((const float4*)src)[i];
    ushort4 o;
    o.x = f2bf(v.x); o.y = f2bf(v.y); o.z = f2bf(v.z); o.w = f2bf(v.w);
    ((ushort4*)dst)[i] = o;
  }
}

// ---- GEMM: C[M,N] = A[M,K] * B[N,K]^T  (bf16 in, f32 acc) ----
// Double-buffered LDS, 2-phase pipeline: STAGE(t+1) issued BEFORE compute(t),
// single vmcnt(0)+barrier per K-tile (T3 minimum recipe).
// EPI: 0 = store bf16 (u)           1 = silu -> bf16 (sel_h)
//      2 = store f32 (final out)
//      3 = dual quadrants a,b : h_t = sigmoid(a)*h_prev + tanh(b)*u  -> f32out
//      4 = dual quadrants c,d : y   = tanh(c)*h_t + d[s]*sigmoid(dd)*u -> bf16out
template <int EPI, int KD, int NCOLS>
__global__ __launch_bounds__(256) void k_gemm(const u16* __restrict__ A,
                                              const u16* __restrict__ Bsrc,
                                              float* __restrict__ f32out,
                                              u16* __restrict__ bfout,
                                              const float* __restrict__ hprev,
                                              const u16* __restrict__ ubf,
                                              const float* __restrict__ dvec) {
  // LDS: buffer b at smem + b*16384; within buffer: A tile [0,8192), B tile [8192,16384)
  extern __shared__ __align__(16) char smem[];
  const int tid = threadIdx.x;
  const int w = tid >> 6;      // wave 0..3
  const int l = tid & 63;      // lane
  const int i_half = w >> 1;   // row half
  const int j_mat  = w & 1;    // col half / matrix select (dual)
  const int wm = i_half * 64;
  const int wn = j_mat * 64;
  const int m0 = blockIdx.y * 128;

  // ---- staging addressing (per-thread, loop-invariant) ----
  const int r0 = w * 32 + (l >> 2);  // tile row for instr 0
  const int r1 = r0 + 16;            // tile row for instr 1
  const int c8 = (l & 3) * 8;        // k-offset (elements)
  const size_t aoff0 = ((size_t)(m0 + r0) * KD + c8) * 2;
  const size_t aoff1 = ((size_t)(m0 + r1) * KD + c8) * 2;
  size_t boff0, boff1;
  if constexpr (EPI <= 2) {
    const int n0 = blockIdx.x * 128;
    boff0 = ((size_t)(n0 + r0) * KD + c8) * 2;
    boff1 = ((size_t)(n0 + r1) * KD + c8) * 2;
  } else {
    const int n0s = blockIdx.x * 64;
    const int q0 = (EPI == 3) ? 0 : 2;
    boff0 = ((size_t)((q0 + (r0 >> 6)) * STATE + n0s + (r0 & 63)) * KD + c8) * 2;
    boff1 = ((size_t)((q0 + (r1 >> 6)) * STATE + n0s + (r1 & 63)) * KD + c8) * 2;
  }
  const char* gA = (const char*)A;
  const char* gB = (const char*)Bsrc;
  const unsigned la0 = (unsigned)(w * 2048 + l * 16);
  const unsigned la1 = la0 + 1024;
  const unsigned lb0 = 8192u + la0;
  const unsigned lb1 = 8192u + la1;

  f32x4 acc[4][4];
#pragma unroll
  for (int a = 0; a < 4; ++a)
#pragma unroll
    for (int b = 0; b < 4; ++b) acc[a][b] = f32x4{0.f, 0.f, 0.f, 0.f};

  const char* Apf = smem + (size_t)(wm + (l & 15)) * 64 + (l >> 4) * 16;
  const char* Bpf = smem + 8192 + (size_t)(wm * 0 + wn + (l & 15)) * 64 + (l >> 4) * 16;

  auto stage = [&](int t, unsigned bufoff) {
    const size_t kb = (size_t)t * 64;   // 32 elems * 2B per K-tile
    gload16(gA + aoff0 + kb, smem + bufoff + la0);
    gload16(gA + aoff1 + kb, smem + bufoff + la1);
    gload16(gB + boff0 + kb, smem + bufoff + lb0);
    gload16(gB + boff1 + kb, smem + bufoff + lb1);
  };
  auto compute = [&](unsigned bufoff) {
    short8_t av[4], bv[4];
#pragma unroll
    for (int t = 0; t < 4; ++t) {
      av[t] = *(const short8_t*)(Apf + bufoff + t * 1024);
      bv[t] = *(const short8_t*)(Bpf + bufoff + t * 1024);
    }
#pragma unroll
    for (int im = 0; im < 4; ++im)
#pragma unroll
      for (int in = 0; in < 4; ++in)
        acc[im][in] = mfma_bf16(av[im], bv[in], acc[im][in]);
  };

  constexpr int NT = KD / 32;   // K-tiles (even for K=1024/2048)
  stage(0, 0);
  asm volatile("s_waitcnt vmcnt(0)" ::: "memory");
  __syncthreads();

#pragma unroll 1
  for (int t = 0; t < NT; t += 2) {
    if (t + 1 < NT) stage(t + 1, 16384u);
    compute(0u);
    asm volatile("s_waitcnt vmcnt(0)" ::: "memory");
    __syncthreads();
    if (t + 2 < NT) stage(t + 2, 0u);
    compute(16384u);
    asm volatile("s_waitcnt vmcnt(0)" ::: "memory");
    __syncthreads();
  }

  const int lr0 = (l >> 4) << 2;   // C-frag row base within 16x16
  const int lc0 = l & 15;          // C-frag col

  if constexpr (EPI <= 2) {
    const int n0 = blockIdx.x * 128;
    const int row_base = blockIdx.y * 128 + wm + lr0;
    const int col_base = n0 + wn + lc0;
#pragma unroll
    for (int im = 0; im < 4; ++im)
#pragma unroll
      for (int in = 0; in < 4; ++in)
#pragma unroll
        for (int r = 0; r < 4; ++r) {
          const int row = row_base + im * 16 + r;
          const int col = col_base + in * 16;
          const size_t idx = (size_t)row * NCOLS + col;
          float v = acc[im][in][r];
          if constexpr (EPI == 0) {
            bfout[idx] = f2bf(v);
          } else if constexpr (EPI == 1) {
            bfout[idx] = f2bf(v * sigmoidf_(v));
          } else {
            f32out[idx] = v;
          }
        }
  } else {
    // dual: wave j=1 ships its (b or d) accumulators through LDS to wave j=0
    float* xch = (float*)smem;     // 2 x [64][65] f32; safe: loop-final barrier passed
    if (j_mat == 1) {
#pragma unroll
      for (int im = 0; im < 4; ++im)
#pragma unroll
        for (int in = 0; in < 4; ++in)
#pragma unroll
          for (int r = 0; r < 4; ++r)
            xch[i_half * 4160 + (im * 16 + lr0 + r) * 65 + in * 16 + lc0] = acc[im][in][r];
    }
    __syncthreads();
    if (j_mat == 0) {
      const int n0s = blockIdx.x * 64;
#pragma unroll
      for (int im = 0; im < 4; ++im)
#pragma unroll
        for (int in = 0; in < 4; ++in)
#pragma unroll
          for (int r = 0; r < 4; ++r) {
            const int lrow = im * 16 + lr0 + r;
            const int lcol = in * 16 + lc0;
            const float own = acc[im][in][r];                        // a_raw or c_raw
            const float oth = xch[i_half * 4160 + lrow * 65 + lcol]; // b_raw or d_raw
            const int grow = blockIdx.y * 128 + i_half * 64 + lrow;
            const int s = n0s + lcol;
            const size_t idx = (size_t)grow * STATE + s;
            const float uu = bf2f(ubf[idx]);
            if constexpr (EPI == 3) {
              const float at = sigmoidf_(own);
              const float bt = tanhf_(oth);
              f32out[idx] = at * hprev[idx] + bt * uu;               // h_t
            } else {
              const float ct = tanhf_(own);
              const float dt = sigmoidf_(oth);
              bfout[idx] = f2bf(ct * hprev[idx] + dvec[s] * dt * uu); // y (hprev = h_t)
            }
          }
    }
  }
}

extern "C" void kernel_launch(void* const* d_in, const int* in_sizes, int n_in,
                              void* d_out, int out_size, void* d_ws, size_t ws_size,
                              hipStream_t stream) {
  const float* x   = (const float*)d_in[0];
  const float* h0  = (const float*)d_in[1];
  const float* Win = (const float*)d_in[2];
  const float* Wsi = (const float*)d_in[3];
  const float* Wso = (const float*)d_in[4];
  const float* Wou = (const float*)d_in[5];
  const float* dv  = (const float*)d_in[6];
  float* out  = (float*)d_out;
  float* hout = out + (size_t)NB * DIMX;   // second output: h_t

  u16* ws = (u16*)d_ws;
  size_t o = 0;
  u16* xb   = ws + o; o += (size_t)NB * DIMX;        // x bf16
  u16* ub   = ws + o; o += (size_t)NB * STATE;       // u bf16
  u16* yb   = ws + o; o += (size_t)NB * STATE;       // y bf16
  u16* sh   = ws + o; o += (size_t)NB * SELH;        // sel_h bf16
  u16* wib  = ws + o; o += (size_t)STATE * DIMX;     // W_in bf16
  u16* wsib = ws + o; o += (size_t)SELH * DIMX;      // W_sel_in bf16
  u16* wsob = ws + o; o += (size_t)4 * STATE * SELH; // W_sel_out bf16
  u16* wob  = ws + o; o += (size_t)DIMX * STATE;     // W_out bf16

  k_f32_to_bf16<<<1024, 256, 0, stream>>>(x,   xb,   NB * DIMX / 4);
  k_f32_to_bf16<<<256,  256, 0, stream>>>(Win, wib,  STATE * DIMX / 4);
  k_f32_to_bf16<<<128,  256, 0, stream>>>(Wsi, wsib, SELH * DIMX / 4);
  k_f32_to_bf16<<<512,  256, 0, stream>>>(Wso, wsob, 4 * STATE * SELH / 4);
  k_f32_to_bf16<<<256,  256, 0, stream>>>(Wou, wob,  DIMX * STATE / 4);

  const dim3 blk(256);
  // u = x @ W_in^T
  k_gemm<0, DIMX, STATE><<<dim3(STATE / 128, NB / 128), blk, 32768, stream>>>(
      xb, wib, nullptr, ub, nullptr, nullptr, nullptr);
  // sel_h = silu(x @ W_sel_in^T)
  k_gemm<1, DIMX, SELH><<<dim3(SELH / 128, NB / 128), blk, 32768, stream>>>(
      xb, wsib, nullptr, sh, nullptr, nullptr, nullptr);
  // h_t = sigmoid(a)*h_prev + tanh(b)*u   (a,b quadrants of sel)
  k_gemm<3, SELH, 0><<<dim3(STATE / 64, NB / 128), blk, 33280, stream>>>(
      sh, wsob, hout, nullptr, h0, ub, nullptr);
  // y = tanh(c)*h_t + d*sigmoid(dd)*u     (c,d quadrants of sel)
  k_gemm<4, SELH, 0><<<dim3(STATE / 64, NB / 128), blk, 33280, stream>>>(
      sh, wsob, nullptr, yb, hout, ub, dv);
  // out = y @ W_out^T
  k_gemm<2, STATE, DIMX><<<dim3(DIMX / 128, NB / 128), blk, 32768, stream>>>(
      yb, wob, out, nullptr, nullptr, nullptr, nullptr);
}

// Round 5
// 1009.393 us; speedup vs baseline: 1.1453x; 1.0919x over previous
//
#include <hip/hip_runtime.h>
#include <hip/hip_bf16.h>
#include <cstdint>

#define NB    16384
#define DIMX  2048
#define STATE 2048
#define SELH  1024

typedef unsigned short u16;
typedef short  short8_t __attribute__((ext_vector_type(8)));
typedef float  f32x4    __attribute__((ext_vector_type(4)));

__device__ __forceinline__ u16 f2bf(float f) {
  unsigned u = __builtin_bit_cast(unsigned, f);
  u += 0x7fffu + ((u >> 16) & 1u);   // RNE
  return (u16)(u >> 16);
}
__device__ __forceinline__ float bf2f(u16 h) {
  unsigned u = ((unsigned)h) << 16;
  return __builtin_bit_cast(float, u);
}
__device__ __forceinline__ float sigmoidf_(float x) { return 1.f / (1.f + __expf(-x)); }
__device__ __forceinline__ float tanhf_(float x)    { return 2.f / (1.f + __expf(-2.f * x)) - 1.f; }

__device__ __forceinline__ f32x4 mfma_bf16(short8_t a, short8_t b, f32x4 c) {
  return __builtin_amdgcn_mfma_f32_16x16x32_bf16(a, b, c, 0, 0, 0);
}

// ---- async global->LDS, 16B per lane ----
__device__ __forceinline__ void gload16(const void* g, const void* l) {
  __builtin_amdgcn_global_load_lds(
      (const __attribute__((address_space(1))) unsigned int*)(uintptr_t)g,
      (__attribute__((address_space(3))) unsigned int*)(unsigned int)(uintptr_t)l,
      16, 0, 0);
}

// ---- f32 -> bf16 convert, vectorized ----
__global__ __launch_bounds__(256) void k_f32_to_bf16(const float* __restrict__ src,
                                                     u16* __restrict__ dst, int n4) {
  int i = blockIdx.x * blockDim.x + threadIdx.x;
  int stride = gridDim.x * blockDim.x;
  for (; i < n4; i += stride) {
    float4 v = ((const float4*)src)[i];
    ushort4 o;
    o.x = f2bf(v.x); o.y = f2bf(v.y); o.z = f2bf(v.z); o.w = f2bf(v.w);
    ((ushort4*)dst)[i] = o;
  }
}

// ---- GEMM: C[M,N] = A[M,K] * B[N,K]^T  (bf16 in, f32 acc) ----
// 3-buffer LDS pipeline with COUNTED vmcnt (T4).
// Invariant at top of iter t: buf[t%3] is resident for ALL waves.
//   prologue: stage(0); stage(1); vmcnt(4) [buf0 landed]; s_barrier.
//   iter t:   dsread(buf t); stage(t+2); lgkmcnt(0) [WAR]; vmcnt(4) [buf t+1 landed];
//             sched_barrier; s_barrier; MFMA.
// Loads stay in flight across barriers (never drained to 0 in steady state).
// EPI: 0 = store bf16 (u)           1 = silu -> bf16 (sel_h)
//      2 = store f32 (final out)
//      3 = dual quadrants a,b : h_t = sigmoid(a)*h_prev + tanh(b)*u  -> f32out
//      4 = dual quadrants c,d : y   = tanh(c)*h_t + d[s]*sigmoid(dd)*u -> bf16out
template <int EPI, int KD, int NCOLS>
__global__ __launch_bounds__(256) void k_gemm(const u16* __restrict__ A,
                                              const u16* __restrict__ Bsrc,
                                              float* __restrict__ f32out,
                                              u16* __restrict__ bfout,
                                              const float* __restrict__ hprev,
                                              const u16* __restrict__ ubf,
                                              const float* __restrict__ dvec) {
  // LDS: 3 buffers of 16 KB; within buffer: A tile [0,8192), B tile [8192,16384)
  extern __shared__ __align__(16) char smem[];
  const int tid = threadIdx.x;
  const int w = tid >> 6;      // wave 0..3
  const int l = tid & 63;      // lane
  const int i_half = w >> 1;   // row half
  const int j_mat  = w & 1;    // col half / matrix select (dual)
  const int wm = i_half * 64;
  const int wn = j_mat * 64;

  // ---- XCD-aware bijective block swizzle (T1); all grids have nwg%8==0 ----
  const int nwg = gridDim.x * gridDim.y;
  const int bidl = blockIdx.y * gridDim.x + blockIdx.x;
  const int cpx = nwg >> 3;
  const int swz = (bidl & 7) * cpx + (bidl >> 3);
  const int bx = swz % gridDim.x;
  const int by = swz / gridDim.x;

  const int m0 = by * 128;

  // ---- staging addressing (per-thread, loop-invariant) ----
  const int r0 = w * 32 + (l >> 2);  // tile row for instr 0
  const int r1 = r0 + 16;            // tile row for instr 1
  const int c8 = (l & 3) * 8;        // k-offset (elements)
  const size_t aoff0 = ((size_t)(m0 + r0) * KD + c8) * 2;
  const size_t aoff1 = ((size_t)(m0 + r1) * KD + c8) * 2;
  size_t boff0, boff1;
  if constexpr (EPI <= 2) {
    const int n0 = bx * 128;
    boff0 = ((size_t)(n0 + r0) * KD + c8) * 2;
    boff1 = ((size_t)(n0 + r1) * KD + c8) * 2;
  } else {
    const int n0s = bx * 64;
    const int q0 = (EPI == 3) ? 0 : 2;
    boff0 = ((size_t)((q0 + (r0 >> 6)) * STATE + n0s + (r0 & 63)) * KD + c8) * 2;
    boff1 = ((size_t)((q0 + (r1 >> 6)) * STATE + n0s + (r1 & 63)) * KD + c8) * 2;
  }
  const char* gA = (const char*)A;
  const char* gB = (const char*)Bsrc;
  const unsigned la0 = (unsigned)(w * 2048 + l * 16);
  const unsigned la1 = la0 + 1024;
  const unsigned lb0 = 8192u + la0;
  const unsigned lb1 = 8192u + la1;

  f32x4 acc[4][4];
#pragma unroll
  for (int a = 0; a < 4; ++a)
#pragma unroll
    for (int b = 0; b < 4; ++b) acc[a][b] = f32x4{0.f, 0.f, 0.f, 0.f};

  const char* Apf = smem + (size_t)(wm + (l & 15)) * 64 + (l >> 4) * 16;
  const char* Bpf = smem + 8192 + (size_t)(wn + (l & 15)) * 64 + (l >> 4) * 16;

  auto stage = [&](int t, unsigned bufoff) {
    const size_t kb = (size_t)t * 64;   // 32 elems * 2B per K-tile
    gload16(gA + aoff0 + kb, smem + bufoff + la0);
    gload16(gA + aoff1 + kb, smem + bufoff + la1);
    gload16(gB + boff0 + kb, smem + bufoff + lb0);
    gload16(gB + boff1 + kb, smem + bufoff + lb1);
  };

  short8_t av[4], bv[4];
  auto dsread = [&](unsigned bufoff) {
#pragma unroll
    for (int t = 0; t < 4; ++t) {
      av[t] = *(const short8_t*)(Apf + bufoff + t * 1024);
      bv[t] = *(const short8_t*)(Bpf + bufoff + t * 1024);
    }
  };
  auto domfma = [&]() {
#pragma unroll
    for (int im = 0; im < 4; ++im)
#pragma unroll
      for (int in = 0; in < 4; ++in)
        acc[im][in] = mfma_bf16(av[im], bv[in], acc[im][in]);
  };

  constexpr int NT = KD / 32;   // K-tiles (32 or 64)
  unsigned ur = 0u, un = 16384u, uf = 32768u;   // read / next / stage-target buffers

  stage(0, ur);
  stage(1, un);
  // ---- prologue wait: buf0 must be resident before ANY dsread of it ----
  asm volatile("s_waitcnt vmcnt(4)" ::: "memory");   // stage(0)'s 4 loads retired
  __builtin_amdgcn_s_barrier();                      // published to all waves

#pragma unroll 1
  for (int t = 0; t < NT - 2; ++t) {
    dsread(ur);                                      // buf t resident (invariant)
    stage(t + 2, uf);
    asm volatile("s_waitcnt lgkmcnt(0)" ::: "memory"); // own ds_reads done (WAR-safe)
    asm volatile("s_waitcnt vmcnt(4)" ::: "memory");   // buf t+1 landed; t+2 in flight
    __builtin_amdgcn_sched_barrier(0);
    __builtin_amdgcn_s_barrier();
    domfma();
    unsigned tmp = ur; ur = un; un = uf; uf = tmp;
  }
  // t = NT-2: nothing new to stage -> drain the last tile's loads
  dsread(ur);
  asm volatile("s_waitcnt lgkmcnt(0)" ::: "memory");
  asm volatile("s_waitcnt vmcnt(0)" ::: "memory");
  __builtin_amdgcn_sched_barrier(0);
  __builtin_amdgcn_s_barrier();
  domfma();
  { unsigned tmp = ur; ur = un; un = uf; uf = tmp; }
  // t = NT-1: last tile already resident
  dsread(ur);
  domfma();

  const int lr0 = (l >> 4) << 2;   // C-frag row base within 16x16
  const int lc0 = l & 15;          // C-frag col

  if constexpr (EPI <= 2) {
    const int n0 = bx * 128;
    const int row_base = by * 128 + wm + lr0;
    const int col_base = n0 + wn + lc0;
#pragma unroll
    for (int im = 0; im < 4; ++im)
#pragma unroll
      for (int in = 0; in < 4; ++in)
#pragma unroll
        for (int r = 0; r < 4; ++r) {
          const int row = row_base + im * 16 + r;
          const int col = col_base + in * 16;
          const size_t idx = (size_t)row * NCOLS + col;
          float v = acc[im][in][r];
          if constexpr (EPI == 0) {
            bfout[idx] = f2bf(v);
          } else if constexpr (EPI == 1) {
            bfout[idx] = f2bf(v * sigmoidf_(v));
          } else {
            f32out[idx] = v;
          }
        }
  } else {
    // dual: wave j=1 ships its (b or d) accumulators through LDS to wave j=0
    __syncthreads();               // all waves done reading staged tiles before reuse
    float* xch = (float*)smem;     // 2 x [64][65] f32
    if (j_mat == 1) {
#pragma unroll
      for (int im = 0; im < 4; ++im)
#pragma unroll
        for (int in = 0; in < 4; ++in)
#pragma unroll
          for (int r = 0; r < 4; ++r)
            xch[i_half * 4160 + (im * 16 + lr0 + r) * 65 + in * 16 + lc0] = acc[im][in][r];
    }
    __syncthreads();
    if (j_mat == 0) {
      const int n0s = bx * 64;
#pragma unroll
      for (int im = 0; im < 4; ++im)
#pragma unroll
        for (int in = 0; in < 4; ++in)
#pragma unroll
          for (int r = 0; r < 4; ++r) {
            const int lrow = im * 16 + lr0 + r;
            const int lcol = in * 16 + lc0;
            const float own = acc[im][in][r];                        // a_raw or c_raw
            const float oth = xch[i_half * 4160 + lrow * 65 + lcol]; // b_raw or d_raw
            const int grow = by * 128 + i_half * 64 + lrow;
            const int s = n0s + lcol;
            const size_t idx = (size_t)grow * STATE + s;
            const float uu = bf2f(ubf[idx]);
            if constexpr (EPI == 3) {
              const float at = sigmoidf_(own);
              const float bt = tanhf_(oth);
              f32out[idx] = at * hprev[idx] + bt * uu;               // h_t
            } else {
              const float ct = tanhf_(own);
              const float dt = sigmoidf_(oth);
              bfout[idx] = f2bf(ct * hprev[idx] + dvec[s] * dt * uu); // y (hprev = h_t)
            }
          }
    }
  }
}

extern "C" void kernel_launch(void* const* d_in, const int* in_sizes, int n_in,
                              void* d_out, int out_size, void* d_ws, size_t ws_size,
                              hipStream_t stream) {
  const float* x   = (const float*)d_in[0];
  const float* h0  = (const float*)d_in[1];
  const float* Win = (const float*)d_in[2];
  const float* Wsi = (const float*)d_in[3];
  const float* Wso = (const float*)d_in[4];
  const float* Wou = (const float*)d_in[5];
  const float* dv  = (const float*)d_in[6];
  float* out  = (float*)d_out;
  float* hout = out + (size_t)NB * DIMX;   // second output: h_t

  u16* ws = (u16*)d_ws;
  size_t o = 0;
  u16* xb   = ws + o; o += (size_t)NB * DIMX;        // x bf16
  u16* ub   = ws + o; o += (size_t)NB * STATE;       // u bf16
  u16* yb   = ws + o; o += (size_t)NB * STATE;       // y bf16
  u16* sh   = ws + o; o += (size_t)NB * SELH;        // sel_h bf16
  u16* wib  = ws + o; o += (size_t)STATE * DIMX;     // W_in bf16
  u16* wsib = ws + o; o += (size_t)SELH * DIMX;      // W_sel_in bf16
  u16* wsob = ws + o; o += (size_t)4 * STATE * SELH; // W_sel_out bf16
  u16* wob  = ws + o; o += (size_t)DIMX * STATE;     // W_out bf16

  k_f32_to_bf16<<<1024, 256, 0, stream>>>(x,   xb,   NB * DIMX / 4);
  k_f32_to_bf16<<<256,  256, 0, stream>>>(Win, wib,  STATE * DIMX / 4);
  k_f32_to_bf16<<<128,  256, 0, stream>>>(Wsi, wsib, SELH * DIMX / 4);
  k_f32_to_bf16<<<512,  256, 0, stream>>>(Wso, wsob, 4 * STATE * SELH / 4);
  k_f32_to_bf16<<<256,  256, 0, stream>>>(Wou, wob,  DIMX * STATE / 4);

  const dim3 blk(256);
  // u = x @ W_in^T
  k_gemm<0, DIMX, STATE><<<dim3(STATE / 128, NB / 128), blk, 49152, stream>>>(
      xb, wib, nullptr, ub, nullptr, nullptr, nullptr);
  // sel_h = silu(x @ W_sel_in^T)
  k_gemm<1, DIMX, SELH><<<dim3(SELH / 128, NB / 128), blk, 49152, stream>>>(
      xb, wsib, nullptr, sh, nullptr, nullptr, nullptr);
  // h_t = sigmoid(a)*h_prev + tanh(b)*u   (a,b quadrants of sel)
  k_gemm<3, SELH, 0><<<dim3(STATE / 64, NB / 128), blk, 49152, stream>>>(
      sh, wsob, hout, nullptr, h0, ub, nullptr);
  // y = tanh(c)*h_t + d*sigmoid(dd)*u     (c,d quadrants of sel)
  k_gemm<4, SELH, 0><<<dim3(STATE / 64, NB / 128), blk, 49152, stream>>>(
      sh, wsob, nullptr, yb, hout, ub, dv);
  // out = y @ W_out^T
  k_gemm<2, STATE, DIMX><<<dim3(DIMX / 128, NB / 128), blk, 49152, stream>>>(
      yb, wob, out, nullptr, nullptr, nullptr, nullptr);
}

// Round 6
// 969.776 us; speedup vs baseline: 1.1921x; 1.0409x over previous
//
#include <hip/hip_runtime.h>
#include <hip/hip_bf16.h>
#include <cstdint>

#define NB    16384
#define DIMX  2048
#define STATE 2048
#define SELH  1024

typedef unsigned short u16;
typedef short  short8_t __attribute__((ext_vector_type(8)));
typedef float  f32x4    __attribute__((ext_vector_type(4)));

__device__ __forceinline__ u16 f2bf(float f) {
  unsigned u = __builtin_bit_cast(unsigned, f);
  u += 0x7fffu + ((u >> 16) & 1u);   // RNE
  return (u16)(u >> 16);
}
__device__ __forceinline__ float bf2f(u16 h) {
  unsigned u = ((unsigned)h) << 16;
  return __builtin_bit_cast(float, u);
}
__device__ __forceinline__ float sigmoidf_(float x) { return 1.f / (1.f + __expf(-x)); }
__device__ __forceinline__ float tanhf_(float x)    { return 2.f / (1.f + __expf(-2.f * x)) - 1.f; }

__device__ __forceinline__ f32x4 mfma_bf16(short8_t a, short8_t b, f32x4 c) {
  return __builtin_amdgcn_mfma_f32_16x16x32_bf16(a, b, c, 0, 0, 0);
}

// ---- async global->LDS, 16B per lane ----
__device__ __forceinline__ void gload16(const void* g, const void* l) {
  __builtin_amdgcn_global_load_lds(
      (const __attribute__((address_space(1))) unsigned int*)(uintptr_t)g,
      (__attribute__((address_space(3))) unsigned int*)(unsigned int)(uintptr_t)l,
      16, 0, 0);
}

// ---- f32 -> bf16 convert, vectorized ----
__global__ __launch_bounds__(256) void k_f32_to_bf16(const float* __restrict__ src,
                                                     u16* __restrict__ dst, int n4) {
  int i = blockIdx.x * blockDim.x + threadIdx.x;
  int stride = gridDim.x * blockDim.x;
  for (; i < n4; i += stride) {
    float4 v = ((const float4*)src)[i];
    ushort4 o;
    o.x = f2bf(v.x); o.y = f2bf(v.y); o.z = f2bf(v.z); o.w = f2bf(v.w);
    ((ushort4*)dst)[i] = o;
  }
}

// ---- GEMM: C[M,N] = A[M,K] * B[N,K]^T  (bf16 in, f32 acc) ----
// 3-buffer LDS pipeline with COUNTED vmcnt (T4).
// NOTE (R6): NO XCD block swizzle. gridDim.x is a multiple of 8, so natural
// round-robin dispatch pins bx ≡ xcd (mod 8): each XCD's L2 holds only its
// 2-4 B-panels (L2-stationary weights). R5's chunked swizzle broke this
// (FETCH 280->607 MB). Identity mapping IS the locality optimum here.
// Invariant at top of iter t: buf[t%3] is resident for ALL waves.
// EPI: 0 = store bf16 (u)           1 = silu -> bf16 (sel_h)
//      2 = store f32 (final out)
//      3 = dual quadrants a,b : h_t = sigmoid(a)*h_prev + tanh(b)*u  -> f32out
//      4 = dual quadrants c,d : y   = tanh(c)*h_t + d[s]*sigmoid(dd)*u -> bf16out
template <int EPI, int KD, int NCOLS>
__global__ __launch_bounds__(256) void k_gemm(const u16* __restrict__ A,
                                              const u16* __restrict__ Bsrc,
                                              float* __restrict__ f32out,
                                              u16* __restrict__ bfout,
                                              const float* __restrict__ hprev,
                                              const u16* __restrict__ ubf,
                                              const float* __restrict__ dvec) {
  // LDS: 3 buffers of 16 KB; within buffer: A tile [0,8192), B tile [8192,16384)
  extern __shared__ __align__(16) char smem[];
  const int tid = threadIdx.x;
  const int w = tid >> 6;      // wave 0..3
  const int l = tid & 63;      // lane
  const int i_half = w >> 1;   // row half
  const int j_mat  = w & 1;    // col half / matrix select (dual)
  const int wm = i_half * 64;
  const int wn = j_mat * 64;

  const int bx = blockIdx.x;
  const int by = blockIdx.y;
  const int m0 = by * 128;

  // ---- staging addressing (per-thread, loop-invariant) ----
  const int r0 = w * 32 + (l >> 2);  // tile row for instr 0
  const int r1 = r0 + 16;            // tile row for instr 1
  const int c8 = (l & 3) * 8;        // k-offset (elements)
  const size_t aoff0 = ((size_t)(m0 + r0) * KD + c8) * 2;
  const size_t aoff1 = ((size_t)(m0 + r1) * KD + c8) * 2;
  size_t boff0, boff1;
  if constexpr (EPI <= 2) {
    const int n0 = bx * 128;
    boff0 = ((size_t)(n0 + r0) * KD + c8) * 2;
    boff1 = ((size_t)(n0 + r1) * KD + c8) * 2;
  } else {
    const int n0s = bx * 64;
    const int q0 = (EPI == 3) ? 0 : 2;
    boff0 = ((size_t)((q0 + (r0 >> 6)) * STATE + n0s + (r0 & 63)) * KD + c8) * 2;
    boff1 = ((size_t)((q0 + (r1 >> 6)) * STATE + n0s + (r1 & 63)) * KD + c8) * 2;
  }
  const char* gA = (const char*)A;
  const char* gB = (const char*)Bsrc;
  const unsigned la0 = (unsigned)(w * 2048 + l * 16);
  const unsigned la1 = la0 + 1024;
  const unsigned lb0 = 8192u + la0;
  const unsigned lb1 = 8192u + la1;

  f32x4 acc[4][4];
#pragma unroll
  for (int a = 0; a < 4; ++a)
#pragma unroll
    for (int b = 0; b < 4; ++b) acc[a][b] = f32x4{0.f, 0.f, 0.f, 0.f};

  const char* Apf = smem + (size_t)(wm + (l & 15)) * 64 + (l >> 4) * 16;
  const char* Bpf = smem + 8192 + (size_t)(wn + (l & 15)) * 64 + (l >> 4) * 16;

  auto stage = [&](int t, unsigned bufoff) {
    const size_t kb = (size_t)t * 64;   // 32 elems * 2B per K-tile
    gload16(gA + aoff0 + kb, smem + bufoff + la0);
    gload16(gA + aoff1 + kb, smem + bufoff + la1);
    gload16(gB + boff0 + kb, smem + bufoff + lb0);
    gload16(gB + boff1 + kb, smem + bufoff + lb1);
  };

  short8_t av[4], bv[4];
  auto dsread = [&](unsigned bufoff) {
#pragma unroll
    for (int t = 0; t < 4; ++t) {
      av[t] = *(const short8_t*)(Apf + bufoff + t * 1024);
      bv[t] = *(const short8_t*)(Bpf + bufoff + t * 1024);
    }
  };
  auto domfma = [&]() {
#pragma unroll
    for (int im = 0; im < 4; ++im)
#pragma unroll
      for (int in = 0; in < 4; ++in)
        acc[im][in] = mfma_bf16(av[im], bv[in], acc[im][in]);
  };

  constexpr int NT = KD / 32;   // K-tiles (32 or 64)
  unsigned ur = 0u, un = 16384u, uf = 32768u;   // read / next / stage-target buffers

  stage(0, ur);
  stage(1, un);
  // ---- prologue wait: buf0 must be resident before ANY dsread of it ----
  asm volatile("s_waitcnt vmcnt(4)" ::: "memory");   // stage(0)'s 4 loads retired
  __builtin_amdgcn_s_barrier();                      // published to all waves

#pragma unroll 1
  for (int t = 0; t < NT - 2; ++t) {
    dsread(ur);                                      // buf t resident (invariant)
    stage(t + 2, uf);
    asm volatile("s_waitcnt lgkmcnt(0)" ::: "memory"); // own ds_reads done (WAR-safe)
    asm volatile("s_waitcnt vmcnt(4)" ::: "memory");   // buf t+1 landed; t+2 in flight
    __builtin_amdgcn_sched_barrier(0);
    __builtin_amdgcn_s_barrier();
    domfma();
    unsigned tmp = ur; ur = un; un = uf; uf = tmp;
  }
  // t = NT-2: nothing new to stage -> drain the last tile's loads
  dsread(ur);
  asm volatile("s_waitcnt lgkmcnt(0)" ::: "memory");
  asm volatile("s_waitcnt vmcnt(0)" ::: "memory");
  __builtin_amdgcn_sched_barrier(0);
  __builtin_amdgcn_s_barrier();
  domfma();
  { unsigned tmp = ur; ur = un; un = uf; uf = tmp; }
  // t = NT-1: last tile already resident
  dsread(ur);
  domfma();

  const int lr0 = (l >> 4) << 2;   // C-frag row base within 16x16
  const int lc0 = l & 15;          // C-frag col

  if constexpr (EPI <= 2) {
    const int n0 = bx * 128;
    const int row_base = by * 128 + wm + lr0;
    const int col_base = n0 + wn + lc0;
#pragma unroll
    for (int im = 0; im < 4; ++im)
#pragma unroll
      for (int in = 0; in < 4; ++in)
#pragma unroll
        for (int r = 0; r < 4; ++r) {
          const int row = row_base + im * 16 + r;
          const int col = col_base + in * 16;
          const size_t idx = (size_t)row * NCOLS + col;
          float v = acc[im][in][r];
          if constexpr (EPI == 0) {
            bfout[idx] = f2bf(v);
          } else if constexpr (EPI == 1) {
            bfout[idx] = f2bf(v * sigmoidf_(v));
          } else {
            f32out[idx] = v;
          }
        }
  } else {
    // dual: wave j=1 ships its (b or d) accumulators through LDS to wave j=0
    __syncthreads();               // all waves done reading staged tiles before reuse
    float* xch = (float*)smem;     // 2 x [64][65] f32
    if (j_mat == 1) {
#pragma unroll
      for (int im = 0; im < 4; ++im)
#pragma unroll
        for (int in = 0; in < 4; ++in)
#pragma unroll
          for (int r = 0; r < 4; ++r)
            xch[i_half * 4160 + (im * 16 + lr0 + r) * 65 + in * 16 + lc0] = acc[im][in][r];
    }
    __syncthreads();
    if (j_mat == 0) {
      const int n0s = bx * 64;
#pragma unroll
      for (int im = 0; im < 4; ++im)
#pragma unroll
        for (int in = 0; in < 4; ++in)
#pragma unroll
          for (int r = 0; r < 4; ++r) {
            const int lrow = im * 16 + lr0 + r;
            const int lcol = in * 16 + lc0;
            const float own = acc[im][in][r];                        // a_raw or c_raw
            const float oth = xch[i_half * 4160 + lrow * 65 + lcol]; // b_raw or d_raw
            const int grow = by * 128 + i_half * 64 + lrow;
            const int s = n0s + lcol;
            const size_t idx = (size_t)grow * STATE + s;
            const float uu = bf2f(ubf[idx]);
            if constexpr (EPI == 3) {
              const float at = sigmoidf_(own);
              const float bt = tanhf_(oth);
              f32out[idx] = at * hprev[idx] + bt * uu;               // h_t
            } else {
              const float ct = tanhf_(own);
              const float dt = sigmoidf_(oth);
              bfout[idx] = f2bf(ct * hprev[idx] + dvec[s] * dt * uu); // y (hprev = h_t)
            }
          }
    }
  }
}

extern "C" void kernel_launch(void* const* d_in, const int* in_sizes, int n_in,
                              void* d_out, int out_size, void* d_ws, size_t ws_size,
                              hipStream_t stream) {
  const float* x   = (const float*)d_in[0];
  const float* h0  = (const float*)d_in[1];
  const float* Win = (const float*)d_in[2];
  const float* Wsi = (const float*)d_in[3];
  const float* Wso = (const float*)d_in[4];
  const float* Wou = (const float*)d_in[5];
  const float* dv  = (const float*)d_in[6];
  float* out  = (float*)d_out;
  float* hout = out + (size_t)NB * DIMX;   // second output: h_t

  u16* ws = (u16*)d_ws;
  size_t o = 0;
  u16* xb   = ws + o; o += (size_t)NB * DIMX;        // x bf16
  u16* ub   = ws + o; o += (size_t)NB * STATE;       // u bf16
  u16* yb   = ws + o; o += (size_t)NB * STATE;       // y bf16
  u16* sh   = ws + o; o += (size_t)NB * SELH;        // sel_h bf16
  u16* wib  = ws + o; o += (size_t)STATE * DIMX;     // W_in bf16
  u16* wsib = ws + o; o += (size_t)SELH * DIMX;      // W_sel_in bf16
  u16* wsob = ws + o; o += (size_t)4 * STATE * SELH; // W_sel_out bf16
  u16* wob  = ws + o; o += (size_t)DIMX * STATE;     // W_out bf16

  k_f32_to_bf16<<<1024, 256, 0, stream>>>(x,   xb,   NB * DIMX / 4);
  k_f32_to_bf16<<<256,  256, 0, stream>>>(Win, wib,  STATE * DIMX / 4);
  k_f32_to_bf16<<<128,  256, 0, stream>>>(Wsi, wsib, SELH * DIMX / 4);
  k_f32_to_bf16<<<512,  256, 0, stream>>>(Wso, wsob, 4 * STATE * SELH / 4);
  k_f32_to_bf16<<<256,  256, 0, stream>>>(Wou, wob,  DIMX * STATE / 4);

  const dim3 blk(256);
  // u = x @ W_in^T
  k_gemm<0, DIMX, STATE><<<dim3(STATE / 128, NB / 128), blk, 49152, stream>>>(
      xb, wib, nullptr, ub, nullptr, nullptr, nullptr);
  // sel_h = silu(x @ W_sel_in^T)
  k_gemm<1, DIMX, SELH><<<dim3(SELH / 128, NB / 128), blk, 49152, stream>>>(
      xb, wsib, nullptr, sh, nullptr, nullptr, nullptr);
  // h_t = sigmoid(a)*h_prev + tanh(b)*u   (a,b quadrants of sel)
  k_gemm<3, SELH, 0><<<dim3(STATE / 64, NB / 128), blk, 49152, stream>>>(
      sh, wsob, hout, nullptr, h0, ub, nullptr);
  // y = tanh(c)*h_t + d*sigmoid(dd)*u     (c,d quadrants of sel)
  k_gemm<4, SELH, 0><<<dim3(STATE / 64, NB / 128), blk, 49152, stream>>>(
      sh, wsob, nullptr, yb, hout, ub, dv);
  // out = y @ W_out^T
  k_gemm<2, STATE, DIMX><<<dim3(DIMX / 128, NB / 128), blk, 49152, stream>>>(
      yb, wob, out, nullptr, nullptr, nullptr, nullptr);
}

// Round 7
// 811.042 us; speedup vs baseline: 1.4254x; 1.1957x over previous
//
#include <hip/hip_runtime.h>
#include <hip/hip_bf16.h>
#include <cstdint>

#define NB    16384
#define DIMX  2048
#define STATE 2048
#define SELH  1024

typedef unsigned short u16;
typedef short  short8_t __attribute__((ext_vector_type(8)));
typedef float  f32x4    __attribute__((ext_vector_type(4)));

__device__ __forceinline__ u16 f2bf(float f) {
  unsigned u = __builtin_bit_cast(unsigned, f);
  u += 0x7fffu + ((u >> 16) & 1u);   // RNE
  return (u16)(u >> 16);
}
__device__ __forceinline__ float bf2f(u16 h) {
  unsigned u = ((unsigned)h) << 16;
  return __builtin_bit_cast(float, u);
}
__device__ __forceinline__ float sigmoidf_(float x) { return 1.f / (1.f + __expf(-x)); }
__device__ __forceinline__ float tanhf_(float x)    { return 2.f / (1.f + __expf(-2.f * x)) - 1.f; }

__device__ __forceinline__ f32x4 mfma_bf16(short8_t a, short8_t b, f32x4 c) {
  return __builtin_amdgcn_mfma_f32_16x16x32_bf16(a, b, c, 0, 0, 0);
}

// ---- async global->LDS, 16B per lane ----
__device__ __forceinline__ void gload16(const void* g, const void* l) {
  __builtin_amdgcn_global_load_lds(
      (const __attribute__((address_space(1))) unsigned int*)(uintptr_t)g,
      (__attribute__((address_space(3))) unsigned int*)(unsigned int)(uintptr_t)l,
      16, 0, 0);
}

// ---- f32 -> bf16 convert, vectorized ----
__global__ __launch_bounds__(256) void k_f32_to_bf16(const float* __restrict__ src,
                                                     u16* __restrict__ dst, int n4) {
  int i = blockIdx.x * blockDim.x + threadIdx.x;
  int stride = gridDim.x * blockDim.x;
  for (; i < n4; i += stride) {
    float4 v = ((const float4*)src)[i];
    ushort4 o;
    o.x = f2bf(v.x); o.y = f2bf(v.y); o.z = f2bf(v.z); o.w = f2bf(v.w);
    ((ushort4*)dst)[i] = o;
  }
}

// =====================================================================
// 256x256 8-phase GEMM (T2 swizzle + T3/T4 counted-vmcnt + T5 setprio)
// C[M,N] = A[M,K] * B[N,K]^T, bf16 in, f32 acc. 512 thr = 8 waves (2Mx4N).
// LDS 128 KiB: A[d][rowhalf] = d*32768 + rh*16384 ([128 rows][64k], 128B rows,
//              read-swizzle cb ^= (row&7)<<4, conflict-free);
//              B[d][khalf]   = 65536 + d*32768 + kh*16384 ([256 rows][32k],
//              64B rows, cb ^= (row&3)<<4, residual 4-way on 8 reads/tile).
// Staging: linear gload_lds dest + inverse-swizzled per-lane global source.
// K-tile = 4 phases: {kk0,nf01},{kk0,nf23},{kk1,nf23},{kk1,nf01}; one
// half-tile staged per phase (rotation A0',A1',B0',B1'); waits: vmcnt(4)@p2
// (B-kh1 of current tile), vmcnt(2)@p4 (A0',A1',B0' of next tile). Never 0
// in steady state.
// EPI: 0 bf16-store | 1 silu->bf16 | 2 f32-store
//      3 dual a,b: h_t = sig(a)*h_prev + tanh(b)*u -> f32
//      4 dual c,d: y = tanh(c)*h_t + d[s]*sig(dd)*u -> bf16
// Dual B-row map: tile row r: wcb=r>>6, sub=r&63, quad=sub>>5, soff=sub&31
//   -> W row (q0+quad)*STATE + s0 + wcb*32 + soff. Wave frag nf pairs
//   (nf, nf+2) = (a,b) at the SAME state col => register-local gating.
// =====================================================================
template <int EPI, int KD, int NCOLS>
__global__ __launch_bounds__(512, 2) void k_gemm256(const u16* __restrict__ A,
                                                    const u16* __restrict__ Bsrc,
                                                    float* __restrict__ f32out,
                                                    u16* __restrict__ bfout,
                                                    const float* __restrict__ hprev,
                                                    const u16* __restrict__ ubf,
                                                    const float* __restrict__ dvec) {
  __shared__ __align__(16) char smem[131072];
  const int tid = threadIdx.x;
  const int w = tid >> 6, l = tid & 63;
  const int wr = w >> 2, wc = w & 3;
  const int bx = blockIdx.x, by = blockIdx.y;
  const int m0 = by * 256;

  // ---- ds_read bases (swizzled) ----
  const unsigned aAddr0 = (unsigned)(wr * 16384 + (l & 15) * 128 +
                                     (((l >> 4) * 16) ^ ((l & 7) << 4)));
  const unsigned aAddr1 = aAddr0 ^ 64u;
  const unsigned bAddr0 = (unsigned)(65536 + (wc * 64 + (l & 15)) * 64 +
                                     (((l >> 4) * 16) ^ ((l & 3) << 4)));
  const unsigned bAddr1 = bAddr0 + 16384u;

  // ---- staging: per-thread global sources (inverse-swizzled) ----
  const int rA = tid >> 3;                                   // A row (j adds 64, rh adds 128)
  const int kA = ((tid & 7) ^ ((tid >> 3) & 7)) * 8;         // A k-off (elems)
  const u16* aSrc = A + (size_t)(m0 + rA) * KD + kA;

  const int rB = tid >> 2;                                   // B row, j=0 (j=1 adds 128)
  const int kB = ((tid & 3) ^ ((tid >> 2) & 3)) * 8;         // B k-off (elems)
  size_t bRow0, bRow1;
  if constexpr (EPI <= 2) {
    bRow0 = (size_t)bx * 256 + rB;
    bRow1 = bRow0 + 128;
  } else {
    const int q0 = (EPI == 3) ? 0 : 2;
    const int s0 = bx * 128;
    const int sub0 = rB & 63, wcb0 = rB >> 6;
    const int r1 = rB + 128;
    const int sub1 = r1 & 63, wcb1 = r1 >> 6;
    bRow0 = (size_t)(q0 + (sub0 >> 5)) * STATE + s0 + wcb0 * 32 + (sub0 & 31);
    bRow1 = (size_t)(q0 + (sub1 >> 5)) * STATE + s0 + wcb1 * 32 + (sub1 & 31);
  }
  const u16* bSrc0 = Bsrc + bRow0 * KD + kB;
  const u16* bSrc1 = Bsrc + bRow1 * KD + kB;

  auto stageA = [&](int k0n, int rh, unsigned dstD) {
    const u16* sp = aSrc + (size_t)rh * 128 * KD + k0n;
    gload16(sp,               smem + dstD + (unsigned)rh * 16384u + (unsigned)tid * 16u);
    gload16(sp + 64 * KD,     smem + dstD + (unsigned)rh * 16384u + 8192u + (unsigned)tid * 16u);
  };
  auto stageB = [&](int k0n, int kh, unsigned dstD) {
    const int kk = k0n + kh * 32;
    gload16(bSrc0 + kk, smem + 65536u + dstD + (unsigned)kh * 16384u + (unsigned)tid * 16u);
    gload16(bSrc1 + kk, smem + 65536u + dstD + (unsigned)kh * 16384u + 8192u + (unsigned)tid * 16u);
  };

  f32x4 acc[8][4];
#pragma unroll
  for (int i = 0; i < 8; ++i)
#pragma unroll
    for (int j = 0; j < 4; ++j) acc[i][j] = f32x4{0.f, 0.f, 0.f, 0.f};

  short8_t av[8], bvN[2], bvM[2];

#define LOAD_AV(D, KK)                                                         \
  _Pragma("unroll") for (int mf = 0; mf < 8; ++mf)                             \
      av[mf] = *(const short8_t*)(smem + ((KK) ? aAddr1 : aAddr0) +            \
                                  (D) * 32768u + mf * 2048u);
#define LOAD_BV(R, I, NF, D, KK)                                               \
  R[I] = *(const short8_t*)(smem + ((KK) ? bAddr1 : bAddr0) + (D) * 32768u +   \
                            (NF) * 1024u);
#define MFMA8x2(BV, NFA, NFB)                                                  \
  __builtin_amdgcn_s_setprio(1);                                               \
  _Pragma("unroll") for (int mf = 0; mf < 8; ++mf) {                           \
    acc[mf][NFA] = mfma_bf16(av[mf], BV[0], acc[mf][NFA]);                     \
    acc[mf][NFB] = mfma_bf16(av[mf], BV[1], acc[mf][NFB]);                     \
  }                                                                            \
  __builtin_amdgcn_s_setprio(0);

#define KTILE(D, K0, DO_STAGE, K0N, LASTT)                                     \
  {                                                                            \
    /* P1: kk0, nf0/1 */                                                       \
    LOAD_AV(D, 0);                                                             \
    LOAD_BV(bvN, 0, 0, D, 0); LOAD_BV(bvN, 1, 1, D, 0);                        \
    if (DO_STAGE) stageA(K0N, 0, (D ^ 1) * 32768u);                            \
    __builtin_amdgcn_s_barrier();                                              \
    MFMA8x2(bvN, 0, 1);                                                        \
    __builtin_amdgcn_s_barrier();                                              \
    /* P2: kk0, nf2/3 */                                                       \
    LOAD_BV(bvM, 0, 2, D, 0); LOAD_BV(bvM, 1, 3, D, 0);                        \
    if (DO_STAGE) stageA(K0N, 1, (D ^ 1) * 32768u);                            \
    if (LASTT) { asm volatile("s_waitcnt vmcnt(0)" ::: "memory"); }            \
    else       { asm volatile("s_waitcnt vmcnt(4)" ::: "memory"); }            \
    __builtin_amdgcn_s_barrier();                                              \
    MFMA8x2(bvM, 2, 3);                                                        \
    __builtin_amdgcn_s_barrier();                                              \
    /* P3: kk1, nf2/3 */                                                       \
    LOAD_AV(D, 1);                                                             \
    LOAD_BV(bvM, 0, 2, D, 1); LOAD_BV(bvM, 1, 3, D, 1);                        \
    if (DO_STAGE) stageB(K0N, 0, (D ^ 1) * 32768u);                            \
    __builtin_amdgcn_s_barrier();                                              \
    MFMA8x2(bvM, 2, 3);                                                        \
    __builtin_amdgcn_s_barrier();                                              \
    /* P4: kk1, nf0/1 */                                                       \
    LOAD_BV(bvN, 0, 0, D, 1); LOAD_BV(bvN, 1, 1, D, 1);                        \
    if (DO_STAGE) stageB(K0N, 1, (D ^ 1) * 32768u);                            \
    if (!LASTT) { asm volatile("s_waitcnt vmcnt(2)" ::: "memory"); }           \
    __builtin_amdgcn_s_barrier();                                              \
    MFMA8x2(bvN, 0, 1);                                                        \
    __builtin_amdgcn_s_barrier();                                              \
  }

  // ---- prologue: stage T0 fully; A0,A1,B0 landed before P1 ----
  stageA(0, 0, 0u); stageA(0, 1, 0u); stageB(0, 0, 0u); stageB(0, 1, 0u);
  asm volatile("s_waitcnt vmcnt(2)" ::: "memory");
  __builtin_amdgcn_s_barrier();

  constexpr int NT = KD / 64;
  int k0 = 0;
#pragma unroll 1
  for (int T = 0; T < NT - 2; T += 2) {
    KTILE(0, k0, true, k0 + 64, false);
    KTILE(1, k0 + 64, true, k0 + 128, false);
    k0 += 128;
  }
  KTILE(0, k0, true, k0 + 64, false);   // T = NT-2: stages last tile
  KTILE(1, k0 + 64, false, 0, true);    // T = NT-1: no stage, drain

#undef KTILE
#undef MFMA8x2
#undef LOAD_BV
#undef LOAD_AV

  // ---- epilogue ----
  const int rbase = m0 + wr * 128 + ((l >> 4) << 2);
  if constexpr (EPI <= 2) {
    const int cbase = bx * 256 + wc * 64 + (l & 15);
#pragma unroll
    for (int mf = 0; mf < 8; ++mf)
#pragma unroll
      for (int nf = 0; nf < 4; ++nf)
#pragma unroll
        for (int r = 0; r < 4; ++r) {
          const int row = rbase + mf * 16 + r;
          const int col = cbase + nf * 16;
          const size_t idx = (size_t)row * NCOLS + col;
          const float v = acc[mf][nf][r];
          if constexpr (EPI == 0) {
            bfout[idx] = f2bf(v);
          } else if constexpr (EPI == 1) {
            bfout[idx] = f2bf(v * sigmoidf_(v));
          } else {
            f32out[idx] = v;
          }
        }
  } else {
    const int sbase = bx * 128 + wc * 32 + (l & 15);
#pragma unroll
    for (int mf = 0; mf < 8; ++mf)
#pragma unroll
      for (int nf = 0; nf < 2; ++nf)
#pragma unroll
        for (int r = 0; r < 4; ++r) {
          const int row = rbase + mf * 16 + r;
          const int s = sbase + nf * 16;
          const size_t idx = (size_t)row * STATE + s;
          const float own = acc[mf][nf][r];       // a_raw / c_raw
          const float oth = acc[mf][nf + 2][r];   // b_raw / d_raw
          const float uu = bf2f(ubf[idx]);
          if constexpr (EPI == 3) {
            f32out[idx] = sigmoidf_(own) * hprev[idx] + tanhf_(oth) * uu;   // h_t
          } else {
            bfout[idx] = f2bf(tanhf_(own) * hprev[idx] +
                              dvec[s] * sigmoidf_(oth) * uu);               // y
          }
        }
  }
}

extern "C" void kernel_launch(void* const* d_in, const int* in_sizes, int n_in,
                              void* d_out, int out_size, void* d_ws, size_t ws_size,
                              hipStream_t stream) {
  const float* x   = (const float*)d_in[0];
  const float* h0  = (const float*)d_in[1];
  const float* Win = (const float*)d_in[2];
  const float* Wsi = (const float*)d_in[3];
  const float* Wso = (const float*)d_in[4];
  const float* Wou = (const float*)d_in[5];
  const float* dv  = (const float*)d_in[6];
  float* out  = (float*)d_out;
  float* hout = out + (size_t)NB * DIMX;   // second output: h_t

  u16* ws = (u16*)d_ws;
  size_t o = 0;
  u16* xb   = ws + o; o += (size_t)NB * DIMX;        // x bf16
  u16* ub   = ws + o; o += (size_t)NB * STATE;       // u bf16
  u16* yb   = ws + o; o += (size_t)NB * STATE;       // y bf16
  u16* sh   = ws + o; o += (size_t)NB * SELH;        // sel_h bf16
  u16* wib  = ws + o; o += (size_t)STATE * DIMX;     // W_in bf16
  u16* wsib = ws + o; o += (size_t)SELH * DIMX;      // W_sel_in bf16
  u16* wsob = ws + o; o += (size_t)4 * STATE * SELH; // W_sel_out bf16
  u16* wob  = ws + o; o += (size_t)DIMX * STATE;     // W_out bf16

  k_f32_to_bf16<<<1024, 256, 0, stream>>>(x,   xb,   NB * DIMX / 4);
  k_f32_to_bf16<<<256,  256, 0, stream>>>(Win, wib,  STATE * DIMX / 4);
  k_f32_to_bf16<<<128,  256, 0, stream>>>(Wsi, wsib, SELH * DIMX / 4);
  k_f32_to_bf16<<<512,  256, 0, stream>>>(Wso, wsob, 4 * STATE * SELH / 4);
  k_f32_to_bf16<<<256,  256, 0, stream>>>(Wou, wob,  DIMX * STATE / 4);

  const dim3 blk(512);
  // u = x @ W_in^T
  k_gemm256<0, DIMX, STATE><<<dim3(STATE / 256, NB / 256), blk, 0, stream>>>(
      xb, wib, nullptr, ub, nullptr, nullptr, nullptr);
  // sel_h = silu(x @ W_sel_in^T)
  k_gemm256<1, DIMX, SELH><<<dim3(SELH / 256, NB / 256), blk, 0, stream>>>(
      xb, wsib, nullptr, sh, nullptr, nullptr, nullptr);
  // h_t = sigmoid(a)*h_prev + tanh(b)*u   (a,b quadrants of sel)
  k_gemm256<3, SELH, 0><<<dim3(STATE / 128, NB / 256), blk, 0, stream>>>(
      sh, wsob, hout, nullptr, h0, ub, nullptr);
  // y = tanh(c)*h_t + d*sigmoid(dd)*u     (c,d quadrants of sel)
  k_gemm256<4, SELH, 0><<<dim3(STATE / 128, NB / 256), blk, 0, stream>>>(
      sh, wsob, nullptr, yb, hout, ub, dv);
  // out = y @ W_out^T
  k_gemm256<2, STATE, DIMX><<<dim3(DIMX / 256, NB / 256), blk, 0, stream>>>(
      yb, wob, out, nullptr, nullptr, nullptr, nullptr);
}

// Round 8
// 798.250 us; speedup vs baseline: 1.4483x; 1.0160x over previous
//
#include <hip/hip_runtime.h>
#include <hip/hip_bf16.h>
#include <cstdint>

#define NB    16384
#define DIMX  2048
#define STATE 2048
#define SELH  1024

typedef unsigned short u16;
typedef short  short8_t __attribute__((ext_vector_type(8)));
typedef float  f32x4    __attribute__((ext_vector_type(4)));

__device__ __forceinline__ u16 f2bf(float f) {
  unsigned u = __builtin_bit_cast(unsigned, f);
  u += 0x7fffu + ((u >> 16) & 1u);   // RNE
  return (u16)(u >> 16);
}
__device__ __forceinline__ float bf2f(u16 h) {
  unsigned u = ((unsigned)h) << 16;
  return __builtin_bit_cast(float, u);
}
__device__ __forceinline__ float sigmoidf_(float x) { return 1.f / (1.f + __expf(-x)); }
__device__ __forceinline__ float tanhf_(float x)    { return 2.f / (1.f + __expf(-2.f * x)) - 1.f; }

__device__ __forceinline__ f32x4 mfma_bf16(short8_t a, short8_t b, f32x4 c) {
  return __builtin_amdgcn_mfma_f32_16x16x32_bf16(a, b, c, 0, 0, 0);
}

// ---- async global->LDS, 16B per lane ----
__device__ __forceinline__ void gload16(const void* g, const void* l) {
  __builtin_amdgcn_global_load_lds(
      (const __attribute__((address_space(1))) unsigned int*)(uintptr_t)g,
      (__attribute__((address_space(3))) unsigned int*)(unsigned int)(uintptr_t)l,
      16, 0, 0);
}

// aligned LDS vector read (ensure ds_read_b128, never scalarized)
#define LDS_V(p) (*(const short8_t*)__builtin_assume_aligned((const void*)(p), 16))

// ---- f32 -> bf16 convert, vectorized ----
__global__ __launch_bounds__(256) void k_f32_to_bf16(const float* __restrict__ src,
                                                     u16* __restrict__ dst, int n4) {
  int i = blockIdx.x * blockDim.x + threadIdx.x;
  int stride = gridDim.x * blockDim.x;
  for (; i < n4; i += stride) {
    float4 v = ((const float4*)src)[i];
    ushort4 o;
    o.x = f2bf(v.x); o.y = f2bf(v.y); o.z = f2bf(v.z); o.w = f2bf(v.w);
    ((ushort4*)dst)[i] = o;
  }
}

// =====================================================================
// 256x256 8-phase GEMM (T2 swizzle + T3/T4 counted-vmcnt + T5 setprio)
// C[M,N] = A[M,K] * B[N,K]^T, bf16 in, f32 acc. 512 thr = 8 waves (2Mx4N).
// EPI: 0 bf16-store | 1 silu->bf16 | 2 f32-store
//      3 FUSED 4-quad gate: B-tile row r -> W row
//         ((r>>4)&3)*STATE + bx*64 + (r>>6)*16 + (r&15)
//         => wave wc, frag nf = quad nf at state-col bx*64 + wc*16 + (l&15):
//         acc[mf][0..3] = (a,b,c,d) register-local.
//         h = sig(a)*h_prev + tanh(b)*u  -> f32out
//         y = tanh(c)*h + d[s]*sig(dd)*u -> bfout
// =====================================================================
template <int EPI, int KD, int NCOLS>
__global__ __launch_bounds__(512, 2) void k_gemm256(const u16* __restrict__ A,
                                                    const u16* __restrict__ Bsrc,
                                                    float* __restrict__ f32out,
                                                    u16* __restrict__ bfout,
                                                    const float* __restrict__ hprev,
                                                    const u16* __restrict__ ubf,
                                                    const float* __restrict__ dvec) {
  __shared__ __align__(16) char smem[131072];
  const int tid = threadIdx.x;
  const int w = tid >> 6, l = tid & 63;
  const int wr = w >> 2, wc = w & 3;
  const int bx = blockIdx.x, by = blockIdx.y;
  const int m0 = by * 256;

  // ---- ds_read bases (swizzled) ----
  const unsigned aAddr0 = (unsigned)(wr * 16384 + (l & 15) * 128 +
                                     (((l >> 4) * 16) ^ ((l & 7) << 4)));
  const unsigned aAddr1 = aAddr0 ^ 64u;
  const unsigned bAddr0 = (unsigned)(65536 + (wc * 64 + (l & 15)) * 64 +
                                     (((l >> 4) * 16) ^ ((l & 3) << 4)));
  const unsigned bAddr1 = bAddr0 + 16384u;

  // ---- staging: per-thread global sources (inverse-swizzled) ----
  const int rA = tid >> 3;                                   // A row (rh adds 128)
  const int kA = ((tid & 7) ^ ((tid >> 3) & 7)) * 8;         // A k-off (elems)
  const u16* aSrc = A + (size_t)(m0 + rA) * KD + kA;

  const int rB = tid >> 2;                                   // B tile row (2nd gload +128)
  const int kB = ((tid & 3) ^ ((tid >> 2) & 3)) * 8;         // B k-off (elems)
  size_t bRow0, bRow1;
  if constexpr (EPI <= 2) {
    bRow0 = (size_t)bx * 256 + rB;
    bRow1 = bRow0 + 128;
  } else {
    const int s0 = bx * 64;
    const int r1 = rB + 128;
    bRow0 = (size_t)((rB >> 4) & 3) * STATE + s0 + (rB >> 6) * 16 + (rB & 15);
    bRow1 = (size_t)((r1 >> 4) & 3) * STATE + s0 + (r1 >> 6) * 16 + (r1 & 15);
  }
  const u16* bSrc0 = Bsrc + bRow0 * KD + kB;
  const u16* bSrc1 = Bsrc + bRow1 * KD + kB;

  auto stageA = [&](int k0n, int rh, unsigned dstD) {
    const u16* sp = aSrc + (size_t)rh * 128 * KD + k0n;
    gload16(sp,           smem + dstD + (unsigned)rh * 16384u + (unsigned)tid * 16u);
    gload16(sp + 64 * KD, smem + dstD + (unsigned)rh * 16384u + 8192u + (unsigned)tid * 16u);
  };
  auto stageB = [&](int k0n, int kh, unsigned dstD) {
    const int kk = k0n + kh * 32;
    gload16(bSrc0 + kk, smem + 65536u + dstD + (unsigned)kh * 16384u + (unsigned)tid * 16u);
    gload16(bSrc1 + kk, smem + 65536u + dstD + (unsigned)kh * 16384u + 8192u + (unsigned)tid * 16u);
  };

  f32x4 acc[8][4];
#pragma unroll
  for (int i = 0; i < 8; ++i)
#pragma unroll
    for (int j = 0; j < 4; ++j) acc[i][j] = f32x4{0.f, 0.f, 0.f, 0.f};

  short8_t av[8], bvN[2], bvM[2];

#define LOAD_AV(D, KK)                                                         \
  _Pragma("unroll") for (int mf = 0; mf < 8; ++mf)                             \
      av[mf] = LDS_V(smem + ((KK) ? aAddr1 : aAddr0) + (D) * 32768u + mf * 2048u);
#define LOAD_BV(R, I, NF, D, KK)                                               \
  R[I] = LDS_V(smem + ((KK) ? bAddr1 : bAddr0) + (D) * 32768u + (NF) * 1024u);
#define MFMA8x2(BV, NFA, NFB)                                                  \
  __builtin_amdgcn_s_setprio(1);                                               \
  _Pragma("unroll") for (int mf = 0; mf < 8; ++mf) {                           \
    acc[mf][NFA] = mfma_bf16(av[mf], BV[0], acc[mf][NFA]);                     \
    acc[mf][NFB] = mfma_bf16(av[mf], BV[1], acc[mf][NFB]);                     \
  }                                                                            \
  __builtin_amdgcn_s_setprio(0);

#define KTILE(D, K0, DO_STAGE, K0N, LASTT)                                     \
  {                                                                            \
    /* P1: kk0, nf0/1 */                                                       \
    LOAD_AV(D, 0);                                                             \
    LOAD_BV(bvN, 0, 0, D, 0); LOAD_BV(bvN, 1, 1, D, 0);                        \
    if (DO_STAGE) stageA(K0N, 0, (D ^ 1) * 32768u);                            \
    __builtin_amdgcn_s_barrier();                                              \
    MFMA8x2(bvN, 0, 1);                                                        \
    __builtin_amdgcn_s_barrier();                                              \
    /* P2: kk0, nf2/3 */                                                       \
    LOAD_BV(bvM, 0, 2, D, 0); LOAD_BV(bvM, 1, 3, D, 0);                        \
    if (DO_STAGE) stageA(K0N, 1, (D ^ 1) * 32768u);                            \
    if (LASTT) { asm volatile("s_waitcnt vmcnt(0)" ::: "memory"); }            \
    else       { asm volatile("s_waitcnt vmcnt(4)" ::: "memory"); }            \
    __builtin_amdgcn_s_barrier();                                              \
    MFMA8x2(bvM, 2, 3);                                                        \
    __builtin_amdgcn_s_barrier();                                              \
    /* P3: kk1, nf2/3 */                                                       \
    LOAD_AV(D, 1);                                                             \
    LOAD_BV(bvM, 0, 2, D, 1); LOAD_BV(bvM, 1, 3, D, 1);                        \
    if (DO_STAGE) stageB(K0N, 0, (D ^ 1) * 32768u);                            \
    __builtin_amdgcn_s_barrier();                                              \
    MFMA8x2(bvM, 2, 3);                                                        \
    __builtin_amdgcn_s_barrier();                                              \
    /* P4: kk1, nf0/1 */                                                       \
    LOAD_BV(bvN, 0, 0, D, 1); LOAD_BV(bvN, 1, 1, D, 1);                        \
    if (DO_STAGE) stageB(K0N, 1, (D ^ 1) * 32768u);                            \
    if (!LASTT) { asm volatile("s_waitcnt vmcnt(2)" ::: "memory"); }           \
    __builtin_amdgcn_s_barrier();                                              \
    MFMA8x2(bvN, 0, 1);                                                        \
    __builtin_amdgcn_s_barrier();                                              \
  }

  // ---- prologue: stage T0 fully; A0,A1,B0 landed before P1 ----
  stageA(0, 0, 0u); stageA(0, 1, 0u); stageB(0, 0, 0u); stageB(0, 1, 0u);
  asm volatile("s_waitcnt vmcnt(2)" ::: "memory");
  __builtin_amdgcn_s_barrier();

  constexpr int NT = KD / 64;
  int k0 = 0;
#pragma unroll 1
  for (int T = 0; T < NT - 2; T += 2) {
    KTILE(0, k0, true, k0 + 64, false);
    KTILE(1, k0 + 64, true, k0 + 128, false);
    k0 += 128;
  }
  KTILE(0, k0, true, k0 + 64, false);   // T = NT-2: stages last tile
  KTILE(1, k0 + 64, false, 0, true);    // T = NT-1: no stage, drain

#undef KTILE
#undef MFMA8x2
#undef LOAD_BV
#undef LOAD_AV

  // ---- epilogue ----
  const int rbase = m0 + wr * 128 + ((l >> 4) << 2);
  if constexpr (EPI <= 2) {
    const int cbase = bx * 256 + wc * 64 + (l & 15);
#pragma unroll
    for (int mf = 0; mf < 8; ++mf)
#pragma unroll
      for (int nf = 0; nf < 4; ++nf)
#pragma unroll
        for (int r = 0; r < 4; ++r) {
          const int row = rbase + mf * 16 + r;
          const int col = cbase + nf * 16;
          const size_t idx = (size_t)row * NCOLS + col;
          const float v = acc[mf][nf][r];
          if constexpr (EPI == 0) {
            bfout[idx] = f2bf(v);
          } else if constexpr (EPI == 1) {
            bfout[idx] = f2bf(v * sigmoidf_(v));
          } else {
            f32out[idx] = v;
          }
        }
  } else {
    const int s = bx * 64 + wc * 16 + (l & 15);
    const float dval = dvec[s];
#pragma unroll
    for (int mf = 0; mf < 8; ++mf)
#pragma unroll
      for (int r = 0; r < 4; ++r) {
        const int row = rbase + mf * 16 + r;
        const size_t idx = (size_t)row * STATE + s;
        const float a  = acc[mf][0][r];
        const float b  = acc[mf][1][r];
        const float c  = acc[mf][2][r];
        const float dd = acc[mf][3][r];
        const float uu = bf2f(ubf[idx]);
        const float hp = hprev[idx];
        const float h = sigmoidf_(a) * hp + tanhf_(b) * uu;
        f32out[idx] = h;                                          // h_t
        bfout[idx] = f2bf(tanhf_(c) * h + dval * sigmoidf_(dd) * uu);  // y
      }
  }
}

extern "C" void kernel_launch(void* const* d_in, const int* in_sizes, int n_in,
                              void* d_out, int out_size, void* d_ws, size_t ws_size,
                              hipStream_t stream) {
  const float* x   = (const float*)d_in[0];
  const float* h0  = (const float*)d_in[1];
  const float* Win = (const float*)d_in[2];
  const float* Wsi = (const float*)d_in[3];
  const float* Wso = (const float*)d_in[4];
  const float* Wou = (const float*)d_in[5];
  const float* dv  = (const float*)d_in[6];
  float* out  = (float*)d_out;
  float* hout = out + (size_t)NB * DIMX;   // second output: h_t

  u16* ws = (u16*)d_ws;
  size_t o = 0;
  u16* xb   = ws + o; o += (size_t)NB * DIMX;        // x bf16
  u16* ub   = ws + o; o += (size_t)NB * STATE;       // u bf16
  u16* yb   = ws + o; o += (size_t)NB * STATE;       // y bf16
  u16* sh   = ws + o; o += (size_t)NB * SELH;        // sel_h bf16
  u16* wib  = ws + o; o += (size_t)STATE * DIMX;     // W_in bf16
  u16* wsib = ws + o; o += (size_t)SELH * DIMX;      // W_sel_in bf16
  u16* wsob = ws + o; o += (size_t)4 * STATE * SELH; // W_sel_out bf16
  u16* wob  = ws + o; o += (size_t)DIMX * STATE;     // W_out bf16

  k_f32_to_bf16<<<1024, 256, 0, stream>>>(x,   xb,   NB * DIMX / 4);
  k_f32_to_bf16<<<256,  256, 0, stream>>>(Win, wib,  STATE * DIMX / 4);
  k_f32_to_bf16<<<128,  256, 0, stream>>>(Wsi, wsib, SELH * DIMX / 4);
  k_f32_to_bf16<<<512,  256, 0, stream>>>(Wso, wsob, 4 * STATE * SELH / 4);
  k_f32_to_bf16<<<256,  256, 0, stream>>>(Wou, wob,  DIMX * STATE / 4);

  const dim3 blk(512);
  // u = x @ W_in^T
  k_gemm256<0, DIMX, STATE><<<dim3(STATE / 256, NB / 256), blk, 0, stream>>>(
      xb, wib, nullptr, ub, nullptr, nullptr, nullptr);
  // sel_h = silu(x @ W_sel_in^T)
  k_gemm256<1, DIMX, SELH><<<dim3(SELH / 256, NB / 256), blk, 0, stream>>>(
      xb, wsib, nullptr, sh, nullptr, nullptr, nullptr);
  // FUSED: all 4 quadrants of sel -> h_t (f32) AND y (bf16) in one pass
  k_gemm256<3, SELH, 0><<<dim3(STATE / 64, NB / 256), blk, 0, stream>>>(
      sh, wsob, hout, yb, h0, ub, dv);
  // out = y @ W_out^T
  k_gemm256<2, STATE, DIMX><<<dim3(DIMX / 256, NB / 256), blk, 0, stream>>>(
      yb, wob, out, nullptr, nullptr, nullptr, nullptr);
}

// Round 9
// 755.672 us; speedup vs baseline: 1.5299x; 1.0563x over previous
//
#include <hip/hip_runtime.h>
#include <hip/hip_bf16.h>
#include <cstdint>

#define NB    16384
#define DIMX  2048
#define STATE 2048
#define SELH  1024

typedef unsigned short u16;
typedef short  short8_t __attribute__((ext_vector_type(8)));
typedef float  f32x4    __attribute__((ext_vector_type(4)));

__device__ __forceinline__ u16 f2bf(float f) {
  unsigned u = __builtin_bit_cast(unsigned, f);
  u += 0x7fffu + ((u >> 16) & 1u);   // RNE
  return (u16)(u >> 16);
}
__device__ __forceinline__ float bf2f(u16 h) {
  unsigned u = ((unsigned)h) << 16;
  return __builtin_bit_cast(float, u);
}
__device__ __forceinline__ float sigmoidf_(float x) { return 1.f / (1.f + __expf(-x)); }
__device__ __forceinline__ float tanhf_(float x)    { return 2.f / (1.f + __expf(-2.f * x)) - 1.f; }

__device__ __forceinline__ f32x4 mfma_bf16(short8_t a, short8_t b, f32x4 c) {
  return __builtin_amdgcn_mfma_f32_16x16x32_bf16(a, b, c, 0, 0, 0);
}

// ---- async global->LDS, 16B per lane ----
__device__ __forceinline__ void gload16(const void* g, const void* l) {
  __builtin_amdgcn_global_load_lds(
      (const __attribute__((address_space(1))) unsigned int*)(uintptr_t)g,
      (__attribute__((address_space(3))) unsigned int*)(unsigned int)(uintptr_t)l,
      16, 0, 0);
}

// aligned LDS vector read (ensure ds_read_b128)
#define LDS_V(p) (*(const short8_t*)__builtin_assume_aligned((const void*)(p), 16))

// ---- f32 -> bf16 convert, vectorized ----
__global__ __launch_bounds__(256) void k_f32_to_bf16(const float* __restrict__ src,
                                                     u16* __restrict__ dst, int n4) {
  int i = blockIdx.x * blockDim.x + threadIdx.x;
  int stride = gridDim.x * blockDim.x;
  for (; i < n4; i += stride) {
    float4 v = ((const float4*)src)[i];
    ushort4 o;
    o.x = f2bf(v.x); o.y = f2bf(v.y); o.z = f2bf(v.z); o.w = f2bf(v.w);
    ((ushort4*)dst)[i] = o;
  }
}

// =====================================================================
// 256x256 GEMM, 4-phase K-tile with cross-phase read lookahead.
// Per K-tile: X1{vmcnt(2);bar; read bv01a,ava; stage A0',A1'; MFMA nf01/kk0}
//             X2{vmcnt(4);bar; read bv23a,bv23b,avb; stage B0',B1'; MFMA nf23/kk0}
//             X3{read bv01b; MFMA nf23/kk1}   (no barrier)
//             X4{MFMA nf01/kk1}               (no barrier)
// Only 2 barriers/K-tile; loads never drained to 0 in steady state.
// B-frags issued before A-frags -> compiler partial-lgkm overlap.
// Hazard audit: all buf-D ds_reads consumed by pre-boundary MFMAs (lgkm
// drained); staging targets D^1; vmcnt(2)@X1 lands A0,A1,B0; vmcnt(4)@X2
// lands B1; sched_barrier(0) after each s_barrier stops load hoisting.
// EPI: 0 bf16-store | 1 silu->bf16 | 2 f32-store
//      3 FUSED 4-quad gate -> h_t (f32) + y (bf16)
// =====================================================================
template <int EPI, int KD, int NCOLS>
__global__ __launch_bounds__(512, 2) void k_gemm256(const u16* __restrict__ A,
                                                    const u16* __restrict__ Bsrc,
                                                    float* __restrict__ f32out,
                                                    u16* __restrict__ bfout,
                                                    const float* __restrict__ hprev,
                                                    const u16* __restrict__ ubf,
                                                    const float* __restrict__ dvec) {
  __shared__ __align__(16) char smem[131072];
  const int tid = threadIdx.x;
  const int w = tid >> 6, l = tid & 63;
  const int wr = w >> 2, wc = w & 3;
  const int bx = blockIdx.x, by = blockIdx.y;
  const int m0 = by * 256;

  // ---- ds_read bases (swizzled) ----
  const unsigned aAddr0 = (unsigned)(wr * 16384 + (l & 15) * 128 +
                                     (((l >> 4) * 16) ^ ((l & 7) << 4)));
  const unsigned aAddr1 = aAddr0 ^ 64u;
  const unsigned bAddr0 = (unsigned)(65536 + (wc * 64 + (l & 15)) * 64 +
                                     (((l >> 4) * 16) ^ ((l & 3) << 4)));
  const unsigned bAddr1 = bAddr0 + 16384u;

  // ---- staging: per-thread global sources (inverse-swizzled) ----
  const int rA = tid >> 3;
  const int kA = ((tid & 7) ^ ((tid >> 3) & 7)) * 8;
  const u16* aSrc = A + (size_t)(m0 + rA) * KD + kA;

  const int rB = tid >> 2;
  const int kB = ((tid & 3) ^ ((tid >> 2) & 3)) * 8;
  size_t bRow0, bRow1;
  if constexpr (EPI <= 2) {
    bRow0 = (size_t)bx * 256 + rB;
    bRow1 = bRow0 + 128;
  } else {
    const int s0 = bx * 64;
    const int r1 = rB + 128;
    bRow0 = (size_t)((rB >> 4) & 3) * STATE + s0 + (rB >> 6) * 16 + (rB & 15);
    bRow1 = (size_t)((r1 >> 4) & 3) * STATE + s0 + (r1 >> 6) * 16 + (r1 & 15);
  }
  const u16* bSrc0 = Bsrc + bRow0 * KD + kB;
  const u16* bSrc1 = Bsrc + bRow1 * KD + kB;

  auto stageA = [&](int k0n, int rh, unsigned dstD) {
    const u16* sp = aSrc + (size_t)rh * 128 * KD + k0n;
    gload16(sp,           smem + dstD + (unsigned)rh * 16384u + (unsigned)tid * 16u);
    gload16(sp + 64 * KD, smem + dstD + (unsigned)rh * 16384u + 8192u + (unsigned)tid * 16u);
  };
  auto stageB = [&](int k0n, int kh, unsigned dstD) {
    const int kk = k0n + kh * 32;
    gload16(bSrc0 + kk, smem + 65536u + dstD + (unsigned)kh * 16384u + (unsigned)tid * 16u);
    gload16(bSrc1 + kk, smem + 65536u + dstD + (unsigned)kh * 16384u + 8192u + (unsigned)tid * 16u);
  };

  f32x4 acc[8][4];
#pragma unroll
  for (int i = 0; i < 8; ++i)
#pragma unroll
    for (int j = 0; j < 4; ++j) acc[i][j] = f32x4{0.f, 0.f, 0.f, 0.f};

  short8_t ava[8], avb[8], bv01a[2], bv23a[2], bv23b[2], bv01b[2];

#define KTILE(D, DO_STAGE, K0N, LASTT)                                         \
  {                                                                            \
    /* X1: tile boundary */                                                    \
    if (LASTT) { asm volatile("s_waitcnt vmcnt(0)" ::: "memory"); }            \
    else       { asm volatile("s_waitcnt vmcnt(2)" ::: "memory"); }            \
    __builtin_amdgcn_s_barrier();                                              \
    __builtin_amdgcn_sched_barrier(0);                                         \
    bv01a[0] = LDS_V(smem + bAddr0 + (D) * 32768u);                            \
    bv01a[1] = LDS_V(smem + bAddr0 + (D) * 32768u + 1024u);                    \
    _Pragma("unroll") for (int mf = 0; mf < 8; ++mf)                           \
        ava[mf] = LDS_V(smem + aAddr0 + (D) * 32768u + mf * 2048u);            \
    if (DO_STAGE) { stageA(K0N, 0, (D ^ 1) * 32768u);                          \
                    stageA(K0N, 1, (D ^ 1) * 32768u); }                        \
    __builtin_amdgcn_s_setprio(1);                                             \
    _Pragma("unroll") for (int mf = 0; mf < 8; ++mf) {                         \
      acc[mf][0] = mfma_bf16(ava[mf], bv01a[0], acc[mf][0]);                   \
      acc[mf][1] = mfma_bf16(ava[mf], bv01a[1], acc[mf][1]);                   \
    }                                                                          \
    __builtin_amdgcn_s_setprio(0);                                             \
    /* X2 */                                                                   \
    if (LASTT) { asm volatile("s_waitcnt vmcnt(0)" ::: "memory"); }            \
    else       { asm volatile("s_waitcnt vmcnt(4)" ::: "memory"); }            \
    __builtin_amdgcn_s_barrier();                                              \
    __builtin_amdgcn_sched_barrier(0);                                         \
    bv23a[0] = LDS_V(smem + bAddr0 + (D) * 32768u + 2048u);                    \
    bv23a[1] = LDS_V(smem + bAddr0 + (D) * 32768u + 3072u);                    \
    bv23b[0] = LDS_V(smem + bAddr1 + (D) * 32768u + 2048u);                    \
    bv23b[1] = LDS_V(smem + bAddr1 + (D) * 32768u + 3072u);                    \
    _Pragma("unroll") for (int mf = 0; mf < 8; ++mf)                           \
        avb[mf] = LDS_V(smem + aAddr1 + (D) * 32768u + mf * 2048u);            \
    if (DO_STAGE) { stageB(K0N, 0, (D ^ 1) * 32768u);                          \
                    stageB(K0N, 1, (D ^ 1) * 32768u); }                        \
    __builtin_amdgcn_s_setprio(1);                                             \
    _Pragma("unroll") for (int mf = 0; mf < 8; ++mf) {                         \
      acc[mf][2] = mfma_bf16(ava[mf], bv23a[0], acc[mf][2]);                   \
      acc[mf][3] = mfma_bf16(ava[mf], bv23a[1], acc[mf][3]);                   \
    }                                                                          \
    __builtin_amdgcn_s_setprio(0);                                             \
    /* X3 (no barrier) */                                                      \
    bv01b[0] = LDS_V(smem + bAddr1 + (D) * 32768u);                            \
    bv01b[1] = LDS_V(smem + bAddr1 + (D) * 32768u + 1024u);                    \
    __builtin_amdgcn_s_setprio(1);                                             \
    _Pragma("unroll") for (int mf = 0; mf < 8; ++mf) {                         \
      acc[mf][2] = mfma_bf16(avb[mf], bv23b[0], acc[mf][2]);                   \
      acc[mf][3] = mfma_bf16(avb[mf], bv23b[1], acc[mf][3]);                   \
    }                                                                          \
    __builtin_amdgcn_s_setprio(0);                                             \
    /* X4 (no barrier) */                                                      \
    __builtin_amdgcn_s_setprio(1);                                             \
    _Pragma("unroll") for (int mf = 0; mf < 8; ++mf) {                         \
      acc[mf][0] = mfma_bf16(avb[mf], bv01b[0], acc[mf][0]);                   \
      acc[mf][1] = mfma_bf16(avb[mf], bv01b[1], acc[mf][1]);                   \
    }                                                                          \
    __builtin_amdgcn_s_setprio(0);                                             \
  }

  // ---- prologue: stage T0 fully (waits handled by uniform X1/X2 counts) ----
  stageA(0, 0, 0u); stageA(0, 1, 0u); stageB(0, 0, 0u); stageB(0, 1, 0u);

  constexpr int NT = KD / 64;
  int k0 = 0;
#pragma unroll 1
  for (int T = 0; T < NT - 2; T += 2) {
    KTILE(0, true, k0 + 64, false);
    KTILE(1, true, k0 + 128, false);
    k0 += 128;
  }
  KTILE(0, true, k0 + 64, false);   // T = NT-2: stages last tile
  KTILE(1, false, 0, true);         // T = NT-1: no stage, drain

#undef KTILE

  // ---- epilogue ----
  const int rbase = m0 + wr * 128 + ((l >> 4) << 2);
  if constexpr (EPI <= 2) {
    const int cbase = bx * 256 + wc * 64 + (l & 15);
#pragma unroll
    for (int mf = 0; mf < 8; ++mf)
#pragma unroll
      for (int nf = 0; nf < 4; ++nf)
#pragma unroll
        for (int r = 0; r < 4; ++r) {
          const int row = rbase + mf * 16 + r;
          const int col = cbase + nf * 16;
          const size_t idx = (size_t)row * NCOLS + col;
          const float v = acc[mf][nf][r];
          if constexpr (EPI == 0) {
            bfout[idx] = f2bf(v);
          } else if constexpr (EPI == 1) {
            bfout[idx] = f2bf(v * sigmoidf_(v));
          } else {
            f32out[idx] = v;
          }
        }
  } else {
    const int s = bx * 64 + wc * 16 + (l & 15);
    const float dval = dvec[s];
#pragma unroll
    for (int mf = 0; mf < 8; ++mf)
#pragma unroll
      for (int r = 0; r < 4; ++r) {
        const int row = rbase + mf * 16 + r;
        const size_t idx = (size_t)row * STATE + s;
        const float a  = acc[mf][0][r];
        const float b  = acc[mf][1][r];
        const float c  = acc[mf][2][r];
        const float dd = acc[mf][3][r];
        const float uu = bf2f(ubf[idx]);
        const float hp = hprev[idx];
        const float h = sigmoidf_(a) * hp + tanhf_(b) * uu;
        f32out[idx] = h;                                               // h_t
        bfout[idx] = f2bf(tanhf_(c) * h + dval * sigmoidf_(dd) * uu);  // y
      }
  }
}

extern "C" void kernel_launch(void* const* d_in, const int* in_sizes, int n_in,
                              void* d_out, int out_size, void* d_ws, size_t ws_size,
                              hipStream_t stream) {
  const float* x   = (const float*)d_in[0];
  const float* h0  = (const float*)d_in[1];
  const float* Win = (const float*)d_in[2];
  const float* Wsi = (const float*)d_in[3];
  const float* Wso = (const float*)d_in[4];
  const float* Wou = (const float*)d_in[5];
  const float* dv  = (const float*)d_in[6];
  float* out  = (float*)d_out;
  float* hout = out + (size_t)NB * DIMX;   // second output: h_t

  u16* ws = (u16*)d_ws;
  size_t o = 0;
  u16* xb   = ws + o; o += (size_t)NB * DIMX;        // x bf16
  u16* ub   = ws + o; o += (size_t)NB * STATE;       // u bf16
  u16* yb   = ws + o; o += (size_t)NB * STATE;       // y bf16
  u16* sh   = ws + o; o += (size_t)NB * SELH;        // sel_h bf16
  u16* wib  = ws + o; o += (size_t)STATE * DIMX;     // W_in bf16
  u16* wsib = ws + o; o += (size_t)SELH * DIMX;      // W_sel_in bf16
  u16* wsob = ws + o; o += (size_t)4 * STATE * SELH; // W_sel_out bf16
  u16* wob  = ws + o; o += (size_t)DIMX * STATE;     // W_out bf16

  k_f32_to_bf16<<<1024, 256, 0, stream>>>(x,   xb,   NB * DIMX / 4);
  k_f32_to_bf16<<<256,  256, 0, stream>>>(Win, wib,  STATE * DIMX / 4);
  k_f32_to_bf16<<<128,  256, 0, stream>>>(Wsi, wsib, SELH * DIMX / 4);
  k_f32_to_bf16<<<512,  256, 0, stream>>>(Wso, wsob, 4 * STATE * SELH / 4);
  k_f32_to_bf16<<<256,  256, 0, stream>>>(Wou, wob,  DIMX * STATE / 4);

  const dim3 blk(512);
  // u = x @ W_in^T
  k_gemm256<0, DIMX, STATE><<<dim3(STATE / 256, NB / 256), blk, 0, stream>>>(
      xb, wib, nullptr, ub, nullptr, nullptr, nullptr);
  // sel_h = silu(x @ W_sel_in^T)
  k_gemm256<1, DIMX, SELH><<<dim3(SELH / 256, NB / 256), blk, 0, stream>>>(
      xb, wsib, nullptr, sh, nullptr, nullptr, nullptr);
  // FUSED: all 4 quadrants of sel -> h_t (f32) AND y (bf16) in one pass
  k_gemm256<3, SELH, 0><<<dim3(STATE / 64, NB / 256), blk, 0, stream>>>(
      sh, wsob, hout, yb, h0, ub, dv);
  // out = y @ W_out^T
  k_gemm256<2, STATE, DIMX><<<dim3(DIMX / 256, NB / 256), blk, 0, stream>>>(
      yb, wob, out, nullptr, nullptr, nullptr, nullptr);
}